// Round 7
// baseline (280.734 us; speedup 1.0000x reference)
//
#include <hip/hip_runtime.h>

// ICNN_net_1503238553972 — round 25: 32x32x16 MFMA fhat + register-u3.
// R24 (184.5us) showed VALU cut didn't move time -> latency/issue-bound at
// 2 blocks/CU. This round cuts issue events at constant structure:
//  (1) fhat layers via mfma_f32_32x32x16_f16: wave w = (feat-tile w&3,
//      row-half w>>2); 32 MFMA + 32 B-reads per layer-wave (was 64+64),
//      matrix-pipe cycles -17%, same H bytes/swizzle (shape-independent).
//  (2) srelu'(a3) carried in regs from vfwd2 epilogue; u3 pass becomes
//      register math (kills last 32 v_sqrt + 4 LDS reads per wave).
// f1/ff (16x16) and vnet structure otherwise identical to R24.
// launch_bounds(512,4), grid 1954, LDS 64KB.

typedef _Float16 v2h __attribute__((ext_vector_type(2)));
typedef __fp16   v2hf __attribute__((ext_vector_type(2)));
typedef _Float16 v4h __attribute__((ext_vector_type(4)));
typedef _Float16 v8h __attribute__((ext_vector_type(8)));
typedef float    v4f __attribute__((ext_vector_type(4)));
typedef float    v16f __attribute__((ext_vector_type(16)));

__device__ __forceinline__ v2h cvt_pk(float a, float b){
  v2hf r = __builtin_amdgcn_cvt_pkrtz(a, b);
  union { v2hf f; v2h h; } u; u.f = r;
  return u.h;
}

#define NPTS 500000
#define FUSED_GRID ((NPTS + 255) / 256)   // 1954

// LDS-only barrier: LDS ordering without draining vmcnt (weights in flight)
#define BAR_LDS() asm volatile("s_waitcnt lgkmcnt(0)\n\ts_barrier" ::: "memory")

// offsets in halves inside g_w16
#define OFF_FW    0               // f2..f5: L*16384, [o*128+k]
#define OFF_V2Z   65536           // [j*64+k]
#define OFF_V3Z   69632
#define OFF_V2ZT  73728           // [k*64+j]
#define OFF_V3ZT  77824
#define OFF_VL1T  81920           // [c*64+j]
#define OFF_V2XT  82048
#define OFF_V3XT  82176
#define OFF_VFZ   82304           // [64]
#define OFF_FFW   82368           // [c*128+k]
#define OFF_F1W   82624           // [oc*2+c]
#define OFF_F1P   82880           // f1 padded [o*32+k], k<2 valid else 0
#define OFF_V2XP  86976           // V2x padded [o*32+k], k<2 valid else 0
#define OFF_V3XP  89024           // V3x padded [o*32+k], k<2 valid else 0
#define W16_DATA  91072
#define W16_TOTAL (W16_DATA + 2048)   // zero pad: junk A-rows stay in-bounds

__device__ __align__(16) _Float16 g_w16[W16_TOTAL];

__device__ __forceinline__ float srelu(float x){
  float c = fminf(fmaxf(x, 0.f), 1.f);
  return c * fmaf(-0.5f, c, x);
}
__device__ __forceinline__ float sreluD(float x){
  return fminf(fmaxf(x, 0.f), 1.f);
}

// ---- packed f16 activations (2 f32 in -> 2 f16 out) ----
__device__ __forceinline__ v2h lrelu_pk(float a, float b){
  v2h x = cvt_pk(a, b);
  v2h m = x * (v2h){(_Float16)0.01f, (_Float16)0.01f};
  return __builtin_elementwise_max(x, m);
}
__device__ __forceinline__ v2h srelu_pk(float a, float b){
  v2h x = cvt_pk(a, b);
  const v2h z0 = (v2h){(_Float16)0.f, (_Float16)0.f};
  const v2h o1 = (v2h){(_Float16)1.f, (_Float16)1.f};
  const v2h hf = (v2h){(_Float16)0.5f, (_Float16)0.5f};
  v2h c = __builtin_elementwise_min(__builtin_elementwise_max(x, z0), o1);
  v2h t = x - c * hf;
  return c * t;
}

// ---------------- prep: fp32 weights -> f16 layouts (+zero pad) ----------------
__global__ __launch_bounds__(256) void prep_kernel(
  const float* __restrict__ f2w, const float* __restrict__ f3w,
  const float* __restrict__ f4w, const float* __restrict__ f5w,
  const float* __restrict__ V2z, const float* __restrict__ V3z,
  const float* __restrict__ Vl1, const float* __restrict__ V2x,
  const float* __restrict__ V3x, const float* __restrict__ Vfz,
  const float* __restrict__ ffw, const float* __restrict__ f1w)
{
  const int i = blockIdx.x * 256 + threadIdx.x;
  if (i >= W16_TOTAL) return;
  if (i >= W16_DATA){ g_w16[i] = (_Float16)0.f; return; }
  float v;
  if (i < 65536){
    const float* W[4] = {f2w, f3w, f4w, f5w};
    v = W[i >> 14][i & 16383];
  } else if (i < 69632)  v = V2z[i - 65536];
  else if (i < 73728)    v = V3z[i - 69632];
  else if (i < 77824){ int r = i - 73728; v = V2z[(r & 63)*64 + (r >> 6)]; }
  else if (i < 81920){ int r = i - 77824; v = V3z[(r & 63)*64 + (r >> 6)]; }
  else if (i < 82048){ int r = i - 81920; v = Vl1[(r & 63)*2 + (r >> 6)]; }
  else if (i < 82176){ int r = i - 82048; v = V2x[(r & 63)*2 + (r >> 6)]; }
  else if (i < 82304){ int r = i - 82176; v = V3x[(r & 63)*2 + (r >> 6)]; }
  else if (i < 82368)    v = Vfz[i - 82304];
  else if (i < 82624)    v = ffw[i - 82368];
  else if (i < 82880)    v = f1w[i - 82624];
  else if (i < 86976){ int r = i - 82880; int k = r & 31; v = (k < 2) ? f1w[(r >> 5)*2 + k] : 0.f; }
  else if (i < 89024){ int r = i - 86976; int k = r & 31; v = (k < 2) ? V2x[(r >> 5)*2 + k] : 0.f; }
  else               { int r = i - 89024; int k = r & 31; v = (k < 2) ? V3x[(r >> 5)*2 + k] : 0.f; }
  g_w16[i] = (_Float16)v;
}

// ================= fhat layer: 512 thr, 256 rows, 32x32x16 MFMA =================
// Wave w: feature tile fw = w&3 (feats [fw*32,+32)), row half rh = w>>2
// (rows [rh*128,+128) = 4 col-tiles of 32). 32 MFMA + 32 B-reads/layer.
// H[row][feat] swizzle: byte group (feat>>3) ^ (row&15) — shape-independent,
// so f1/ff (16x16) interoperate unchanged.
__device__ __forceinline__ void fh_layer32(_Float16* H,
    const _Float16* __restrict__ Wl, const float* __restrict__ Bp,
    int fw, int rh, int l)
{
  const int ar = l & 31;   // A feature row within tile; B data row within tile
  const int kg = l >> 5;   // K-group (0/1)

  // bias as C-init: reg tq*4+j -> feature fw*32 + 8*tq + 4*kg + j
  v16f bias;
#pragma unroll
  for (int tq = 0; tq < 4; ++tq){
    const v4f bq = *(const v4f*)(Bp + fw*32 + 8*tq + 4*kg);
    bias[tq*4+0] = bq[0]; bias[tq*4+1] = bq[1];
    bias[tq*4+2] = bq[2]; bias[tq*4+3] = bq[3];
  }
  v16f acc0 = bias, acc1 = bias, acc2 = bias, acc3 = bias;

  const int r0  = rh*128 + ar;
  const int rsw = r0 & 15;           // (r0 + 32k) & 15 == r0 & 15
  const _Float16* wp = Wl + (fw*32 + ar)*128 + kg*8;
  const _Float16* hp = H + r0*128;

#pragma unroll
  for (int kt = 0; kt < 8; ++kt){
    v8h A = *(const v8h*)(wp + kt*16);
    const int sw = ((kt*2 + kg) ^ rsw) << 3;
    v8h B0 = *(const v8h*)(hp            + sw);
    v8h B1 = *(const v8h*)(hp + 32*128   + sw);
    v8h B2 = *(const v8h*)(hp + 64*128   + sw);
    v8h B3 = *(const v8h*)(hp + 96*128   + sw);
    acc0 = __builtin_amdgcn_mfma_f32_32x32x16_f16(A, B0, acc0, 0,0,0);
    acc1 = __builtin_amdgcn_mfma_f32_32x32x16_f16(A, B1, acc1, 0,0,0);
    acc2 = __builtin_amdgcn_mfma_f32_32x32x16_f16(A, B2, acc2, 0,0,0);
    acc3 = __builtin_amdgcn_mfma_f32_32x32x16_f16(A, B3, acc3, 0,0,0);
  }
  BAR_LDS();

  // epilogue: reg quad tq -> features fw*32 + 8*tq + 4*kg + {0..3}
#define FH_EPI32(ACC, NTOFF) { \
  _Float16* op = H + (r0 + NTOFF)*128; \
  _Pragma("unroll") \
  for (int tq = 0; tq < 4; ++tq){ \
    const int coff = (((fw*4 + tq) ^ rsw) << 3) + 4*kg; \
    v4h hv; \
    *(v2h*)&hv       = lrelu_pk(ACC[tq*4+0], ACC[tq*4+1]); \
    *((v2h*)&hv + 1) = lrelu_pk(ACC[tq*4+2], ACC[tq*4+3]); \
    *(v4h*)(op + coff) = hv; \
  } }
  FH_EPI32(acc0, 0)
  FH_EPI32(acc1, 32)
  FH_EPI32(acc2, 64)
  FH_EPI32(acc3, 96)
#undef FH_EPI32
  BAR_LDS();
}

// ================= vnet pieces (ILP-2; Wx@d folded into MFMA) =================
__device__ __forceinline__ void vfwd2_l2(_Float16* zoutA, _Float16* zoutB,
    const _Float16* __restrict__ Wz,   // V2Z [o][k]
    const _Float16* __restrict__ WxP,  // V2XP [o][32], k<2 valid
    const _Float16* __restrict__ Wl1T, // VL1T [2][64]
    v8h BdA, v8h BdB,
    float dA0, float dA1, float dB0, float dB1,
    float* __restrict__ sdA, float* __restrict__ sdB,
    int lm, int q)
{
  v4f accA[4], accB[4];
#pragma unroll
  for (int mt = 0; mt < 4; ++mt){
    accA[mt] = (v4f){0.f,0.f,0.f,0.f};
    accB[mt] = (v4f){0.f,0.f,0.f,0.f};
  }
  const int rs = lm & 7;
#pragma unroll
  for (int mt = 0; mt < 4; ++mt){
    v8h Ax = *(const v8h*)(WxP + (mt*16 + lm)*32 + q*8);
    accA[mt] = __builtin_amdgcn_mfma_f32_16x16x32_f16(Ax, BdA, accA[mt], 0,0,0);
    accB[mt] = __builtin_amdgcn_mfma_f32_16x16x32_f16(Ax, BdB, accB[mt], 0,0,0);
  }
#pragma unroll
  for (int kt = 0; kt < 2; ++kt){
    v8h w0 = *(const v8h*)(Wl1T + kt*32 + q*8);
    v8h w1 = *(const v8h*)(Wl1T + 64 + kt*32 + q*8);
    v8h BA, BB;
#pragma unroll
    for (int j2 = 0; j2 < 4; ++j2){
      const float a0 = (float)w0[2*j2  ], a1 = (float)w0[2*j2+1];
      const float c0 = (float)w1[2*j2  ], c1 = (float)w1[2*j2+1];
      ((v2h*)&BA)[j2] = srelu_pk(fmaf(dA0,a0,dA1*c0), fmaf(dA0,a1,dA1*c1));
      ((v2h*)&BB)[j2] = srelu_pk(fmaf(dB0,a0,dB1*c0), fmaf(dB0,a1,dB1*c1));
    }
#pragma unroll
    for (int mt = 0; mt < 4; ++mt){
      v8h A = *(const v8h*)(Wz + (mt*16 + lm)*64 + kt*32 + q*8);
      accA[mt] = __builtin_amdgcn_mfma_f32_16x16x32_f16(A, BA, accA[mt], 0,0,0);
      accB[mt] = __builtin_amdgcn_mfma_f32_16x16x32_f16(A, BB, accB[mt], 0,0,0);
    }
  }
#pragma unroll
  for (int mt = 0; mt < 4; ++mt){
    const int o0 = mt*16 + q*4;
    const int off = (((o0 >> 3) ^ rs) << 3) + (o0 & 7);
#pragma unroll
    for (int reg = 0; reg < 4; ++reg){
      sdA[mt*4 + reg] = sreluD(accA[mt][reg]);
      sdB[mt*4 + reg] = sreluD(accB[mt][reg]);
    }
    v4h hA, hB;
    *(v2h*)&hA       = srelu_pk(accA[mt][0], accA[mt][1]);
    *((v2h*)&hA + 1) = srelu_pk(accA[mt][2], accA[mt][3]);
    *(v2h*)&hB       = srelu_pk(accB[mt][0], accB[mt][1]);
    *((v2h*)&hB + 1) = srelu_pk(accB[mt][2], accB[mt][3]);
    *(v4h*)(zoutA + lm*64 + off) = hA;
    *(v4h*)(zoutB + lm*64 + off) = hB;
  }
}

// layer-3 fwd (B from LDS); d-term as extra MFMA K-block; srelu'(a3) carried out
__device__ __forceinline__ void vfwd2(const _Float16* zinA, _Float16* zoutA,
    const _Float16* zinB, _Float16* zoutB,
    const _Float16* __restrict__ Wz,   // V3Z
    const _Float16* __restrict__ WxP,  // V3XP [o][32]
    v8h BdA, v8h BdB,
    float* __restrict__ sdA, float* __restrict__ sdB,
    int lm, int q)
{
  v4f accA[4], accB[4];
#pragma unroll
  for (int mt = 0; mt < 4; ++mt){
    accA[mt] = (v4f){0.f,0.f,0.f,0.f};
    accB[mt] = (v4f){0.f,0.f,0.f,0.f};
  }
  const int rs = lm & 7;
#pragma unroll
  for (int mt = 0; mt < 4; ++mt){
    v8h Ax = *(const v8h*)(WxP + (mt*16 + lm)*32 + q*8);
    accA[mt] = __builtin_amdgcn_mfma_f32_16x16x32_f16(Ax, BdA, accA[mt], 0,0,0);
    accB[mt] = __builtin_amdgcn_mfma_f32_16x16x32_f16(Ax, BdB, accB[mt], 0,0,0);
  }
#pragma unroll
  for (int kt = 0; kt < 2; ++kt){
    const int sw = (((kt*4 + q) ^ rs) << 3);
    v8h BA = *(const v8h*)(zinA + lm*64 + sw);
    v8h BB = *(const v8h*)(zinB + lm*64 + sw);
#pragma unroll
    for (int mt = 0; mt < 4; ++mt){
      v8h A = *(const v8h*)(Wz + (mt*16 + lm)*64 + kt*32 + q*8);
      accA[mt] = __builtin_amdgcn_mfma_f32_16x16x32_f16(A, BA, accA[mt], 0,0,0);
      accB[mt] = __builtin_amdgcn_mfma_f32_16x16x32_f16(A, BB, accB[mt], 0,0,0);
    }
  }
#pragma unroll
  for (int mt = 0; mt < 4; ++mt){
    const int o0 = mt*16 + q*4;
    const int off = (((o0 >> 3) ^ rs) << 3) + (o0 & 7);
#pragma unroll
    for (int reg = 0; reg < 4; ++reg){
      sdA[mt*4 + reg] = sreluD(accA[mt][reg]);
      sdB[mt*4 + reg] = sreluD(accB[mt][reg]);
    }
    v4h hA, hB;
    *(v2h*)&hA       = srelu_pk(accA[mt][0], accA[mt][1]);
    *((v2h*)&hA + 1) = srelu_pk(accA[mt][2], accA[mt][3]);
    *(v2h*)&hB       = srelu_pk(accB[mt][0], accB[mt][1]);
    *((v2h*)&hB + 1) = srelu_pk(accB[mt][2], accB[mt][3]);
    *(v4h*)(zoutA + lm*64 + off) = hA;
    *(v4h*)(zoutB + lm*64 + off) = hB;
  }
}

// backward layer-3->2: srelu'(a2) from carried registers
__device__ __forceinline__ void vbwd2(const _Float16* ginA, _Float16* zioA,
    const _Float16* ginB, _Float16* zioB,
    const _Float16* __restrict__ WT,
    const float* __restrict__ sdA, const float* __restrict__ sdB,
    int lm, int q)
{
  v4f accA[4], accB[4];
#pragma unroll
  for (int mt = 0; mt < 4; ++mt){
    accA[mt] = (v4f){0.f,0.f,0.f,0.f};
    accB[mt] = (v4f){0.f,0.f,0.f,0.f};
  }
  const int rs = lm & 7;
#pragma unroll
  for (int kt = 0; kt < 2; ++kt){
    const int sw = (((kt*4 + q) ^ rs) << 3);
    v8h BA = *(const v8h*)(ginA + lm*64 + sw);
    v8h BB = *(const v8h*)(ginB + lm*64 + sw);
#pragma unroll
    for (int mt = 0; mt < 4; ++mt){
      v8h A = *(const v8h*)(WT + (mt*16 + lm)*64 + kt*32 + q*8);
      accA[mt] = __builtin_amdgcn_mfma_f32_16x16x32_f16(A, BA, accA[mt], 0,0,0);
      accB[mt] = __builtin_amdgcn_mfma_f32_16x16x32_f16(A, BB, accB[mt], 0,0,0);
    }
  }
#pragma unroll
  for (int mt = 0; mt < 4; ++mt){
    const int k0 = mt*16 + q*4;
    const int off = (((k0 >> 3) ^ rs) << 3) + (k0 & 7);
    v4h gA, gB;
    *(v2h*)&gA       = cvt_pk(accA[mt][0]*sdA[mt*4+0], accA[mt][1]*sdA[mt*4+1]);
    *((v2h*)&gA + 1) = cvt_pk(accA[mt][2]*sdA[mt*4+2], accA[mt][3]*sdA[mt*4+3]);
    *(v2h*)&gB       = cvt_pk(accB[mt][0]*sdB[mt*4+0], accB[mt][1]*sdB[mt*4+1]);
    *((v2h*)&gB + 1) = cvt_pk(accB[mt][2]*sdB[mt*4+2], accB[mt][3]*sdB[mt*4+3]);
    *(v4h*)(zioA + lm*64 + off) = gA;
    *(v4h*)(zioB + lm*64 + off) = gB;
  }
}

__device__ __forceinline__ void vbwd2_l1(_Float16* zioA, _Float16* zioB,
    const _Float16* __restrict__ WT,   // V2ZT
    const _Float16* __restrict__ Wl1T, // VL1T [2][64]
    float dA0, float dA1, float dB0, float dB1, int lm, int q)
{
  v4f accA[4], accB[4];
#pragma unroll
  for (int mt = 0; mt < 4; ++mt){
    accA[mt] = (v4f){0.f,0.f,0.f,0.f};
    accB[mt] = (v4f){0.f,0.f,0.f,0.f};
  }
  const int rs = lm & 7;
#pragma unroll
  for (int kt = 0; kt < 2; ++kt){
    const int sw = (((kt*4 + q) ^ rs) << 3);
    v8h BA = *(const v8h*)(zioA + lm*64 + sw);
    v8h BB = *(const v8h*)(zioB + lm*64 + sw);
#pragma unroll
    for (int mt = 0; mt < 4; ++mt){
      v8h A = *(const v8h*)(WT + (mt*16 + lm)*64 + kt*32 + q*8);
      accA[mt] = __builtin_amdgcn_mfma_f32_16x16x32_f16(A, BA, accA[mt], 0,0,0);
      accB[mt] = __builtin_amdgcn_mfma_f32_16x16x32_f16(A, BB, accB[mt], 0,0,0);
    }
  }
#pragma unroll
  for (int mt = 0; mt < 4; ++mt){
    const int k0 = mt*16 + q*4;
    const int off = (((k0 >> 3) ^ rs) << 3) + (k0 & 7);
    v4h w0 = *(const v4h*)(Wl1T + k0);
    v4h w1 = *(const v4h*)(Wl1T + 64 + k0);
    float sA[4], sB[4];
#pragma unroll
    for (int reg = 0; reg < 4; ++reg){
      const float a1A = fmaf(dA0, (float)w0[reg], dA1 * (float)w1[reg]);
      const float a1B = fmaf(dB0, (float)w0[reg], dB1 * (float)w1[reg]);
      sA[reg] = accA[mt][reg] * sreluD(a1A);
      sB[reg] = accB[mt][reg] * sreluD(a1B);
    }
    v4h gA, gB;
    *(v2h*)&gA       = cvt_pk(sA[0], sA[1]);
    *((v2h*)&gA + 1) = cvt_pk(sA[2], sA[3]);
    *(v2h*)&gB       = cvt_pk(sB[0], sB[1]);
    *((v2h*)&gB + 1) = cvt_pk(sB[2], sB[3]);
    *(v4h*)(zioA + lm*64 + off) = gA;
    *(v4h*)(zioB + lm*64 + off) = gB;
  }
}

__device__ __forceinline__ void gacc2(v4f& aGA, v4f& aGB,
    const _Float16* __restrict__ WxTbase,
    const _Float16* ZA, const _Float16* ZB, int lm, int q)
{
  const int rs = lm & 7;
#pragma unroll
  for (int kt = 0; kt < 2; ++kt){
    const int sw = (((kt*4 + q) ^ rs) << 3);
    v8h A  = *(const v8h*)(WxTbase + lm*64 + kt*32 + q*8);
    v8h BA = *(const v8h*)(ZA + lm*64 + sw);
    v8h BB = *(const v8h*)(ZB + lm*64 + sw);
    aGA = __builtin_amdgcn_mfma_f32_16x16x32_f16(A, BA, aGA, 0,0,0);
    aGB = __builtin_amdgcn_mfma_f32_16x16x32_f16(A, BB, aGB, 0,0,0);
  }
}

// ================= merged kernel: fhat -> ff(regs) -> vnet -> combine =================
__global__ __launch_bounds__(512, 4) void fused_kernel(
  const float* __restrict__ X, const float* __restrict__ Xst,
  const float* __restrict__ Vfx,
  const float* __restrict__ f1b, const float* __restrict__ f2b,
  const float* __restrict__ f3b, const float* __restrict__ f4b,
  const float* __restrict__ f5b, const float* __restrict__ ffb,
  float* __restrict__ out)
{
  __shared__ __align__(16) char smem[65536];   // fhat H 256x128 | vnet 8x8KB/wave
  _Float16* const H = (_Float16*)smem;

  const int b  = blockIdx.x;
  const int t  = threadIdx.x;
  const int w  = t >> 6;     // 0..7
  const int l  = t & 63;
  const int lm = l & 15;
  const int q  = l >> 4;
  const int rs = lm & 7;
  const int row0 = b*256 + w*32;

  const int r0 = row0 + lm;
  const int r1 = row0 + 16 + lm;
  const int rc0 = r0 < NPTS ? r0 : NPTS-1;
  const int rc1 = r1 < NPTS ? r1 : NPTS-1;
  const float2 x0 = *(const float2*)(X + rc0*2);
  const float2 x1 = *(const float2*)(X + rc1*2);

  // ========== fhat phase ==========
  // ---- f1 via MFMA (16x16): A = f1w padded to K=32, B = x in q==0 lanes ----
  {
    v8h Bx0 = (v8h){(_Float16)0.f,(_Float16)0.f,(_Float16)0.f,(_Float16)0.f,
                    (_Float16)0.f,(_Float16)0.f,(_Float16)0.f,(_Float16)0.f};
    v8h Bx1 = Bx0;
    if (q == 0){
      Bx0[0] = (_Float16)x0.x; Bx0[1] = (_Float16)x0.y;
      Bx1[0] = (_Float16)x1.x; Bx1[1] = (_Float16)x1.y;
    }
#pragma unroll
    for (int mt = 0; mt < 8; ++mt){
      const int o0 = mt*16 + q*4;
      const v4f bv = *(const v4f*)(f1b + o0);
      v8h A = *(const v8h*)(g_w16 + OFF_F1P + (mt*16 + lm)*32 + q*8);
      v4f a0 = __builtin_amdgcn_mfma_f32_16x16x32_f16(A, Bx0, bv, 0,0,0);
      v4f a1 = __builtin_amdgcn_mfma_f32_16x16x32_f16(A, Bx1, bv, 0,0,0);
      const int coff = (((o0 >> 3) ^ lm) << 3) + (o0 & 7);
      v4h h0, h1;
      *(v2h*)&h0       = lrelu_pk(a0[0], a0[1]);
      *((v2h*)&h0 + 1) = lrelu_pk(a0[2], a0[3]);
      *(v2h*)&h1       = lrelu_pk(a1[0], a1[1]);
      *((v2h*)&h1 + 1) = lrelu_pk(a1[2], a1[3]);
      *(v4h*)(H + (w*32 + lm)*128 + coff)      = h0;
      *(v4h*)(H + (w*32 + 16 + lm)*128 + coff) = h1;
    }
  }
  BAR_LDS();

  // ---- f2..f5 via 32x32x16 MFMA ----
  {
    const int fw = w & 3;
    const int rh = w >> 2;
    fh_layer32(H, g_w16 + OFF_FW,         f2b, fw, rh, l);
    fh_layer32(H, g_w16 + OFF_FW + 16384, f3b, fw, rh, l);
    fh_layer32(H, g_w16 + OFF_FW + 32768, f4b, fw, rh, l);
    fh_layer32(H, g_w16 + OFF_FW + 49152, f5b, fw, rh, l);
  }

  // ---- ff via MFMA (16x16) on the wave's OWN rows (w*32..w*32+31) ----
  float fhA0, fhA1, fhB0, fhB1;
  {
    v4f a0 = (v4f){0.f,0.f,0.f,0.f};
    v4f a1 = (v4f){0.f,0.f,0.f,0.f};
#pragma unroll
    for (int kt = 0; kt < 4; ++kt){
      const int sw = ((kt*4 + q) ^ lm) << 3;
      v8h A  = *(const v8h*)(g_w16 + OFF_FFW + lm*128 + kt*32 + q*8);
      v8h B0 = *(const v8h*)(H + (w*32 + lm)*128 + sw);
      v8h B1 = *(const v8h*)(H + (w*32 + 16 + lm)*128 + sw);
      a0 = __builtin_amdgcn_mfma_f32_16x16x32_f16(A, B0, a0, 0,0,0);
      a1 = __builtin_amdgcn_mfma_f32_16x16x32_f16(A, B1, a1, 0,0,0);
    }
    const float fb0 = ffb[0], fb1 = ffb[1];
    fhA0 = a0[0] + fb0; fhA1 = a0[1] + fb1;
    fhB0 = a1[0] + fb0; fhB1 = a1[1] + fb1;
  }

  // ========== vnet phase (wave-local slice) ==========
  _Float16* const ZA2 = (_Float16*)(smem + w*8192);
  _Float16* const ZA3 = ZA2 + 1024;
  _Float16* const ZB2 = ZA2 + 2048;
  _Float16* const ZB3 = ZA2 + 3072;

  const float2 sA = *(const float2*)(Xst + rc0*2);
  const float2 sB = *(const float2*)(Xst + rc1*2);
  const float dA0 = x0.x - sA.x, dA1 = x0.y - sA.y;
  const float dB0 = x1.x - sB.x, dB1 = x1.y - sB.y;
  const float vfx0 = Vfx[0], vfx1 = Vfx[1];

  // d B-fragments for the Wx@d MFMA fold (q==0 lanes carry k=0,1)
  v8h BdA = (v8h){(_Float16)0.f,(_Float16)0.f,(_Float16)0.f,(_Float16)0.f,
                  (_Float16)0.f,(_Float16)0.f,(_Float16)0.f,(_Float16)0.f};
  v8h BdB = BdA;
  if (q == 0){
    BdA[0] = (_Float16)dA0; BdA[1] = (_Float16)dA1;
    BdB[0] = (_Float16)dB0; BdB[1] = (_Float16)dB1;
  }

  // fwd: z2 (srelu'(a2) carried), z3 (srelu'(a3) carried)
  float sdA2[16], sdB2[16], sdA3[16], sdB3[16];
  vfwd2_l2(ZA2, ZB2, g_w16 + OFF_V2Z, g_w16 + OFF_V2XP, g_w16 + OFF_VL1T,
           BdA, BdB, dA0, dA1, dB0, dB1, sdA2, sdB2, lm, q);
  vfwd2(ZA2, ZA3, ZB2, ZB3, g_w16 + OFF_V3Z, g_w16 + OFF_V3XP,
        BdA, BdB, sdA3, sdB3, lm, q);

  // zf head for both (A row 0 = Vfz)
  float VVrA, sfA, VVrB, sfB;
  {
    v4f aSA = (v4f){0.f,0.f,0.f,0.f};
    v4f aSB = (v4f){0.f,0.f,0.f,0.f};
#pragma unroll
    for (int kt = 0; kt < 2; ++kt){
      const int sw = (((kt*4 + q) ^ rs) << 3);
      v8h A  = *(const v8h*)(g_w16 + OFF_VFZ + lm*64 + kt*32 + q*8);
      v8h BA = *(const v8h*)(ZA3 + lm*64 + sw);
      v8h BB = *(const v8h*)(ZB3 + lm*64 + sw);
      aSA = __builtin_amdgcn_mfma_f32_16x16x32_f16(A, BA, aSA, 0,0,0);
      aSB = __builtin_amdgcn_mfma_f32_16x16x32_f16(A, BB, aSB, 0,0,0);
    }
    const float afA = fmaf(vfx0, dA0, fmaf(vfx1, dA1, aSA[0]));
    const float zfA = srelu(afA);
    VVrA = srelu(zfA) + 0.01f * fmaf(dA0, dA0, dA1*dA1);
    sfA  = sreluD(zfA) * sreluD(afA);
    const float afB = fmaf(vfx0, dB0, fmaf(vfx1, dB1, aSB[0]));
    const float zfB = srelu(afB);
    VVrB = srelu(zfB) + 0.01f * fmaf(dB0, dB0, dB1*dB1);
    sfB  = sreluD(zfB) * sreluD(afB);
  }

  // u3 = Vfz * srelu'(a3) — pure register math, writes over Z3 (same offsets
  // as vfwd2's epilogue; zf head's reads complete first by program order)
#pragma unroll
  for (int mt = 0; mt < 4; ++mt){
    const int o0 = mt*16 + q*4;
    const int off = (((o0 >> 3) ^ rs) << 3) + (o0 & 7);
    const v4h vfq = *(const v4h*)(g_w16 + OFF_VFZ + o0);
    v4h uA, uB;
    *(v2h*)&uA       = cvt_pk((float)vfq[0]*sdA3[mt*4+0], (float)vfq[1]*sdA3[mt*4+1]);
    *((v2h*)&uA + 1) = cvt_pk((float)vfq[2]*sdA3[mt*4+2], (float)vfq[3]*sdA3[mt*4+3]);
    *(v2h*)&uB       = cvt_pk((float)vfq[0]*sdB3[mt*4+0], (float)vfq[1]*sdB3[mt*4+1]);
    *((v2h*)&uB + 1) = cvt_pk((float)vfq[2]*sdB3[mt*4+2], (float)vfq[3]*sdB3[mt*4+3]);
    *(v4h*)(ZA3 + lm*64 + off) = uA;
    *(v4h*)(ZB3 + lm*64 + off) = uB;
  }

  // incremental gradV, interleaved with backward (arena reuse)
  v4f aGA = (v4f){0.f,0.f,0.f,0.f};
  v4f aGB = (v4f){0.f,0.f,0.f,0.f};

  gacc2(aGA, aGB, g_w16 + OFF_V3XT, ZA3, ZB3, lm, q);             // L3 (ga3=u3)
  vbwd2(ZA3, ZA2, ZB3, ZB2, g_w16 + OFF_V3ZT, sdA2, sdB2, lm, q); // ga2 -> Z2
  gacc2(aGA, aGB, g_w16 + OFF_V2XT, ZA2, ZB2, lm, q);             // L2
  vbwd2_l1(ZA2, ZB2, g_w16 + OFF_V2ZT, g_w16 + OFF_VL1T,
           dA0, dA1, dB0, dB1, lm, q);                            // ga1 -> Z2
  gacc2(aGA, aGB, g_w16 + OFF_VL1T, ZA2, ZB2, lm, q);             // L1

  const float g0A = fmaf(0.02f, dA0, sfA * (vfx0 + aGA[0]));
  const float g1A = fmaf(0.02f, dA1, sfA * (vfx1 + aGA[1]));
  const float g0B = fmaf(0.02f, dB0, sfB * (vfx0 + aGB[0]));
  const float g1B = fmaf(0.02f, dB1, sfB * (vfx1 + aGB[1]));

  // ========== combine in registers, store out ==========
  if (q == 0){
    if (r0 < NPTS){
      const float Vn  = fmaf(g0A, g0A, g1A*g1A);
      const float num = fmaf(0.1f, VVrA, fmaf(fhA0, g0A, fhA1*g1A));
      const float fm  = fmaxf(num, 0.f) / (Vn + 1e-10f);
      *(float2*)(out + r0*2) =
        make_float2(fmaf(-g0A, fm, fhA0), fmaf(-g1A, fm, fhA1));
    }
    if (r1 < NPTS){
      const float Vn  = fmaf(g0B, g0B, g1B*g1B);
      const float num = fmaf(0.1f, VVrB, fmaf(fhB0, g0B, fhB1*g1B));
      const float fm  = fmaxf(num, 0.f) / (Vn + 1e-10f);
      *(float2*)(out + r1*2) =
        make_float2(fmaf(-g0B, fm, fhB0), fmaf(-g1B, fm, fhB1));
    }
  }
}

extern "C" void kernel_launch(void* const* d_in, const int* in_sizes, int n_in,
                              void* d_out, int out_size, void* d_ws, size_t ws_size,
                              hipStream_t stream)
{
  (void)d_ws; (void)ws_size; (void)n_in; (void)in_sizes; (void)out_size;
  const float* X   = (const float*)d_in[0];
  const float* Xst = (const float*)d_in[1];
  const float* Vl1 = (const float*)d_in[2];
  const float* V2x = (const float*)d_in[3];
  const float* V2z = (const float*)d_in[4];
  const float* V3x = (const float*)d_in[5];
  const float* V3z = (const float*)d_in[6];
  const float* Vfx = (const float*)d_in[7];
  const float* Vfz = (const float*)d_in[8];
  const float* f1w = (const float*)d_in[9];
  const float* f1b = (const float*)d_in[10];
  const float* f2w = (const float*)d_in[11];
  const float* f2b = (const float*)d_in[12];
  const float* f3w = (const float*)d_in[13];
  const float* f3b = (const float*)d_in[14];
  const float* f4w = (const float*)d_in[15];
  const float* f4b = (const float*)d_in[16];
  const float* f5w = (const float*)d_in[17];
  const float* f5b = (const float*)d_in[18];
  const float* ffw = (const float*)d_in[19];
  const float* ffb = (const float*)d_in[20];

  prep_kernel<<<(W16_TOTAL + 255)/256, 256, 0, stream>>>(
      f2w, f3w, f4w, f5w, V2z, V3z, Vl1, V2x, V3x, Vfz, ffw, f1w);
  fused_kernel<<<FUSED_GRID, 512, 0, stream>>>(
      X, Xst, Vfx, f1b, f2b, f3b, f4b, f5b, ffb, (float*)d_out);
}

// Round 8
// 256.779 us; speedup vs baseline: 1.0933x; 1.0933x over previous
//
#include <hip/hip_runtime.h>

// ICNN_net_1503238553972 — round 26: R24 body + pinned register budget.
// R25's regression was SCRATCH SPILL: compiler pins VGPR=64 (8-waves/EU
// heuristic) while occupancy is LDS-bound at 2 blocks/CU = 4 waves/EU
// (128 VGPR allowed). R25's live state spilled ~34MB to HBM (WRITE_SIZE
// 8->32MB). Even R24 lightly spilled (WRITE 8MB vs 4MB out).
// Fix: amdgpu_waves_per_eu(4,4) — allocator targets exactly 4 waves/EU,
// VGPR cap 128, sd-carries and acc tiles stay in registers.
// Body is byte-identical to R24 (184.5us fused, best). Grid 1954, LDS 64KB.

typedef _Float16 v2h __attribute__((ext_vector_type(2)));
typedef __fp16   v2hf __attribute__((ext_vector_type(2)));
typedef _Float16 v4h __attribute__((ext_vector_type(4)));
typedef _Float16 v8h __attribute__((ext_vector_type(8)));
typedef float    v4f __attribute__((ext_vector_type(4)));

__device__ __forceinline__ v2h cvt_pk(float a, float b){
  v2hf r = __builtin_amdgcn_cvt_pkrtz(a, b);
  union { v2hf f; v2h h; } u; u.f = r;
  return u.h;
}

#define NPTS 500000
#define FUSED_GRID ((NPTS + 255) / 256)   // 1954

// LDS-only barrier: LDS ordering without draining vmcnt (weights in flight)
#define BAR_LDS() asm volatile("s_waitcnt lgkmcnt(0)\n\ts_barrier" ::: "memory")

// offsets in halves inside g_w16
#define OFF_FW    0               // f2..f5: L*16384, [o*128+k]
#define OFF_V2Z   65536           // [j*64+k]
#define OFF_V3Z   69632
#define OFF_V2ZT  73728           // [k*64+j]
#define OFF_V3ZT  77824
#define OFF_VL1T  81920           // [c*64+j]
#define OFF_V2XT  82048
#define OFF_V3XT  82176
#define OFF_VFZ   82304           // [64]
#define OFF_FFW   82368           // [c*128+k]
#define OFF_F1W   82624           // [oc*2+c]
#define OFF_F1P   82880           // f1 padded [o*32+k], k<2 valid else 0
#define OFF_V2XP  86976           // V2x padded [o*32+k], k<2 valid else 0
#define OFF_V3XP  89024           // V3x padded [o*32+k], k<2 valid else 0
#define W16_DATA  91072
#define W16_TOTAL (W16_DATA + 2048)   // zero pad: junk A-rows stay in-bounds

__device__ __align__(16) _Float16 g_w16[W16_TOTAL];

__device__ __forceinline__ float srelu(float x){
  float c = fminf(fmaxf(x, 0.f), 1.f);
  return c * fmaf(-0.5f, c, x);
}
__device__ __forceinline__ float sreluD(float x){
  return fminf(fmaxf(x, 0.f), 1.f);
}
__device__ __forceinline__ float sreluD_from_z(float z){
  return fminf(sqrtf(2.f * z), 1.f);
}

// ---- packed f16 activations (2 f32 in -> 2 f16 out) ----
__device__ __forceinline__ v2h lrelu_pk(float a, float b){
  v2h x = cvt_pk(a, b);
  v2h m = x * (v2h){(_Float16)0.01f, (_Float16)0.01f};
  return __builtin_elementwise_max(x, m);
}
__device__ __forceinline__ v2h srelu_pk(float a, float b){
  v2h x = cvt_pk(a, b);
  const v2h z0 = (v2h){(_Float16)0.f, (_Float16)0.f};
  const v2h o1 = (v2h){(_Float16)1.f, (_Float16)1.f};
  const v2h hf = (v2h){(_Float16)0.5f, (_Float16)0.5f};
  v2h c = __builtin_elementwise_min(__builtin_elementwise_max(x, z0), o1);
  v2h t = x - c * hf;
  return c * t;
}

// ---------------- prep: fp32 weights -> f16 layouts (+zero pad) ----------------
__global__ __launch_bounds__(256) void prep_kernel(
  const float* __restrict__ f2w, const float* __restrict__ f3w,
  const float* __restrict__ f4w, const float* __restrict__ f5w,
  const float* __restrict__ V2z, const float* __restrict__ V3z,
  const float* __restrict__ Vl1, const float* __restrict__ V2x,
  const float* __restrict__ V3x, const float* __restrict__ Vfz,
  const float* __restrict__ ffw, const float* __restrict__ f1w)
{
  const int i = blockIdx.x * 256 + threadIdx.x;
  if (i >= W16_TOTAL) return;
  if (i >= W16_DATA){ g_w16[i] = (_Float16)0.f; return; }
  float v;
  if (i < 65536){
    const float* W[4] = {f2w, f3w, f4w, f5w};
    v = W[i >> 14][i & 16383];
  } else if (i < 69632)  v = V2z[i - 65536];
  else if (i < 73728)    v = V3z[i - 69632];
  else if (i < 77824){ int r = i - 73728; v = V2z[(r & 63)*64 + (r >> 6)]; }
  else if (i < 81920){ int r = i - 77824; v = V3z[(r & 63)*64 + (r >> 6)]; }
  else if (i < 82048){ int r = i - 81920; v = Vl1[(r & 63)*2 + (r >> 6)]; }
  else if (i < 82176){ int r = i - 82048; v = V2x[(r & 63)*2 + (r >> 6)]; }
  else if (i < 82304){ int r = i - 82176; v = V3x[(r & 63)*2 + (r >> 6)]; }
  else if (i < 82368)    v = Vfz[i - 82304];
  else if (i < 82624)    v = ffw[i - 82368];
  else if (i < 82880)    v = f1w[i - 82624];
  else if (i < 86976){ int r = i - 82880; int k = r & 31; v = (k < 2) ? f1w[(r >> 5)*2 + k] : 0.f; }
  else if (i < 89024){ int r = i - 86976; int k = r & 31; v = (k < 2) ? V2x[(r >> 5)*2 + k] : 0.f; }
  else               { int r = i - 89024; int k = r & 31; v = (k < 2) ? V3x[(r >> 5)*2 + k] : 0.f; }
  g_w16[i] = (_Float16)v;
}

// ================= fhat layer: 512 thr, 256 rows (R23/R24 form) =================
__device__ __forceinline__ void fh_layer(_Float16* H,
    const _Float16* __restrict__ Wl, const float* __restrict__ Bp,
    int w, int lm, int q)
{
  const v4f bv = *(const v4f*)(Bp + w*16 + q*4);
  v4f acc[16];
#pragma unroll
  for (int nt = 0; nt < 16; ++nt) acc[nt] = bv;

#pragma unroll
  for (int kt = 0; kt < 4; ++kt){
    const int sw = ((kt*4 + q) ^ lm) << 3;
    v8h A = *(const v8h*)(Wl + (w*16 + lm)*128 + kt*32 + q*8);
#pragma unroll
    for (int nt = 0; nt < 16; ++nt){
      v8h B = *(const v8h*)(H + (nt*16 + lm)*128 + sw);
      acc[nt] = __builtin_amdgcn_mfma_f32_16x16x32_f16(A, B, acc[nt], 0,0,0);
    }
  }
  BAR_LDS();
  const int o0 = w*16 + q*4;
  const int coff = (((o0 >> 3) ^ lm) << 3) + (o0 & 7);
#pragma unroll
  for (int nt = 0; nt < 16; ++nt){
    v4h hv;
    *(v2h*)&hv       = lrelu_pk(acc[nt][0], acc[nt][1]);
    *((v2h*)&hv + 1) = lrelu_pk(acc[nt][2], acc[nt][3]);
    *(v4h*)(H + (nt*16 + lm)*128 + coff) = hv;
  }
  BAR_LDS();
}

// ================= vnet pieces (ILP-2; Wx@d folded into MFMA) =================
__device__ __forceinline__ void vfwd2_l2(_Float16* zoutA, _Float16* zoutB,
    const _Float16* __restrict__ Wz,   // V2Z [o][k]
    const _Float16* __restrict__ WxP,  // V2XP [o][32], k<2 valid
    const _Float16* __restrict__ Wl1T, // VL1T [2][64]
    v8h BdA, v8h BdB,
    float dA0, float dA1, float dB0, float dB1,
    float* __restrict__ sdA, float* __restrict__ sdB,
    int lm, int q)
{
  v4f accA[4], accB[4];
#pragma unroll
  for (int mt = 0; mt < 4; ++mt){
    accA[mt] = (v4f){0.f,0.f,0.f,0.f};
    accB[mt] = (v4f){0.f,0.f,0.f,0.f};
  }
  const int rs = lm & 7;
  // d-term: acc += WxP @ Bd
#pragma unroll
  for (int mt = 0; mt < 4; ++mt){
    v8h Ax = *(const v8h*)(WxP + (mt*16 + lm)*32 + q*8);
    accA[mt] = __builtin_amdgcn_mfma_f32_16x16x32_f16(Ax, BdA, accA[mt], 0,0,0);
    accB[mt] = __builtin_amdgcn_mfma_f32_16x16x32_f16(Ax, BdB, accB[mt], 0,0,0);
  }
#pragma unroll
  for (int kt = 0; kt < 2; ++kt){
    v8h w0 = *(const v8h*)(Wl1T + kt*32 + q*8);
    v8h w1 = *(const v8h*)(Wl1T + 64 + kt*32 + q*8);
    v8h BA, BB;
#pragma unroll
    for (int j2 = 0; j2 < 4; ++j2){
      const float a0 = (float)w0[2*j2  ], a1 = (float)w0[2*j2+1];
      const float c0 = (float)w1[2*j2  ], c1 = (float)w1[2*j2+1];
      ((v2h*)&BA)[j2] = srelu_pk(fmaf(dA0,a0,dA1*c0), fmaf(dA0,a1,dA1*c1));
      ((v2h*)&BB)[j2] = srelu_pk(fmaf(dB0,a0,dB1*c0), fmaf(dB0,a1,dB1*c1));
    }
#pragma unroll
    for (int mt = 0; mt < 4; ++mt){
      v8h A = *(const v8h*)(Wz + (mt*16 + lm)*64 + kt*32 + q*8);
      accA[mt] = __builtin_amdgcn_mfma_f32_16x16x32_f16(A, BA, accA[mt], 0,0,0);
      accB[mt] = __builtin_amdgcn_mfma_f32_16x16x32_f16(A, BB, accB[mt], 0,0,0);
    }
  }
#pragma unroll
  for (int mt = 0; mt < 4; ++mt){
    const int o0 = mt*16 + q*4;
    const int off = (((o0 >> 3) ^ rs) << 3) + (o0 & 7);
#pragma unroll
    for (int reg = 0; reg < 4; ++reg){
      sdA[mt*4 + reg] = sreluD(accA[mt][reg]);
      sdB[mt*4 + reg] = sreluD(accB[mt][reg]);
    }
    v4h hA, hB;
    *(v2h*)&hA       = srelu_pk(accA[mt][0], accA[mt][1]);
    *((v2h*)&hA + 1) = srelu_pk(accA[mt][2], accA[mt][3]);
    *(v2h*)&hB       = srelu_pk(accB[mt][0], accB[mt][1]);
    *((v2h*)&hB + 1) = srelu_pk(accB[mt][2], accB[mt][3]);
    *(v4h*)(zoutA + lm*64 + off) = hA;
    *(v4h*)(zoutB + lm*64 + off) = hB;
  }
}

// layer-3 fwd (B from LDS); d-term as extra MFMA K-block
__device__ __forceinline__ void vfwd2(const _Float16* zinA, _Float16* zoutA,
    const _Float16* zinB, _Float16* zoutB,
    const _Float16* __restrict__ Wz,   // V3Z
    const _Float16* __restrict__ WxP,  // V3XP [o][32]
    v8h BdA, v8h BdB, int lm, int q)
{
  v4f accA[4], accB[4];
#pragma unroll
  for (int mt = 0; mt < 4; ++mt){
    accA[mt] = (v4f){0.f,0.f,0.f,0.f};
    accB[mt] = (v4f){0.f,0.f,0.f,0.f};
  }
  const int rs = lm & 7;
#pragma unroll
  for (int mt = 0; mt < 4; ++mt){
    v8h Ax = *(const v8h*)(WxP + (mt*16 + lm)*32 + q*8);
    accA[mt] = __builtin_amdgcn_mfma_f32_16x16x32_f16(Ax, BdA, accA[mt], 0,0,0);
    accB[mt] = __builtin_amdgcn_mfma_f32_16x16x32_f16(Ax, BdB, accB[mt], 0,0,0);
  }
#pragma unroll
  for (int kt = 0; kt < 2; ++kt){
    const int sw = (((kt*4 + q) ^ rs) << 3);
    v8h BA = *(const v8h*)(zinA + lm*64 + sw);
    v8h BB = *(const v8h*)(zinB + lm*64 + sw);
#pragma unroll
    for (int mt = 0; mt < 4; ++mt){
      v8h A = *(const v8h*)(Wz + (mt*16 + lm)*64 + kt*32 + q*8);
      accA[mt] = __builtin_amdgcn_mfma_f32_16x16x32_f16(A, BA, accA[mt], 0,0,0);
      accB[mt] = __builtin_amdgcn_mfma_f32_16x16x32_f16(A, BB, accB[mt], 0,0,0);
    }
  }
#pragma unroll
  for (int mt = 0; mt < 4; ++mt){
    const int o0 = mt*16 + q*4;
    const int off = (((o0 >> 3) ^ rs) << 3) + (o0 & 7);
    v4h hA, hB;
    *(v2h*)&hA       = srelu_pk(accA[mt][0], accA[mt][1]);
    *((v2h*)&hA + 1) = srelu_pk(accA[mt][2], accA[mt][3]);
    *(v2h*)&hB       = srelu_pk(accB[mt][0], accB[mt][1]);
    *((v2h*)&hB + 1) = srelu_pk(accB[mt][2], accB[mt][3]);
    *(v4h*)(zoutA + lm*64 + off) = hA;
    *(v4h*)(zoutB + lm*64 + off) = hB;
  }
}

// backward layer-3->2: srelu'(a2) from carried registers (no z read, no sqrt)
__device__ __forceinline__ void vbwd2(const _Float16* ginA, _Float16* zioA,
    const _Float16* ginB, _Float16* zioB,
    const _Float16* __restrict__ WT,
    const float* __restrict__ sdA, const float* __restrict__ sdB,
    int lm, int q)
{
  v4f accA[4], accB[4];
#pragma unroll
  for (int mt = 0; mt < 4; ++mt){
    accA[mt] = (v4f){0.f,0.f,0.f,0.f};
    accB[mt] = (v4f){0.f,0.f,0.f,0.f};
  }
  const int rs = lm & 7;
#pragma unroll
  for (int kt = 0; kt < 2; ++kt){
    const int sw = (((kt*4 + q) ^ rs) << 3);
    v8h BA = *(const v8h*)(ginA + lm*64 + sw);
    v8h BB = *(const v8h*)(ginB + lm*64 + sw);
#pragma unroll
    for (int mt = 0; mt < 4; ++mt){
      v8h A = *(const v8h*)(WT + (mt*16 + lm)*64 + kt*32 + q*8);
      accA[mt] = __builtin_amdgcn_mfma_f32_16x16x32_f16(A, BA, accA[mt], 0,0,0);
      accB[mt] = __builtin_amdgcn_mfma_f32_16x16x32_f16(A, BB, accB[mt], 0,0,0);
    }
  }
#pragma unroll
  for (int mt = 0; mt < 4; ++mt){
    const int k0 = mt*16 + q*4;
    const int off = (((k0 >> 3) ^ rs) << 3) + (k0 & 7);
    v4h gA, gB;
    *(v2h*)&gA       = cvt_pk(accA[mt][0]*sdA[mt*4+0], accA[mt][1]*sdA[mt*4+1]);
    *((v2h*)&gA + 1) = cvt_pk(accA[mt][2]*sdA[mt*4+2], accA[mt][3]*sdA[mt*4+3]);
    *(v2h*)&gB       = cvt_pk(accB[mt][0]*sdB[mt*4+0], accB[mt][1]*sdB[mt*4+1]);
    *((v2h*)&gB + 1) = cvt_pk(accB[mt][2]*sdB[mt*4+2], accB[mt][3]*sdB[mt*4+3]);
    *(v4h*)(zioA + lm*64 + off) = gA;
    *(v4h*)(zioB + lm*64 + off) = gB;
  }
}

__device__ __forceinline__ void vbwd2_l1(_Float16* zioA, _Float16* zioB,
    const _Float16* __restrict__ WT,   // V2ZT
    const _Float16* __restrict__ Wl1T, // VL1T [2][64]
    float dA0, float dA1, float dB0, float dB1, int lm, int q)
{
  v4f accA[4], accB[4];
#pragma unroll
  for (int mt = 0; mt < 4; ++mt){
    accA[mt] = (v4f){0.f,0.f,0.f,0.f};
    accB[mt] = (v4f){0.f,0.f,0.f,0.f};
  }
  const int rs = lm & 7;
#pragma unroll
  for (int kt = 0; kt < 2; ++kt){
    const int sw = (((kt*4 + q) ^ rs) << 3);
    v8h BA = *(const v8h*)(zioA + lm*64 + sw);
    v8h BB = *(const v8h*)(zioB + lm*64 + sw);
#pragma unroll
    for (int mt = 0; mt < 4; ++mt){
      v8h A = *(const v8h*)(WT + (mt*16 + lm)*64 + kt*32 + q*8);
      accA[mt] = __builtin_amdgcn_mfma_f32_16x16x32_f16(A, BA, accA[mt], 0,0,0);
      accB[mt] = __builtin_amdgcn_mfma_f32_16x16x32_f16(A, BB, accB[mt], 0,0,0);
    }
  }
#pragma unroll
  for (int mt = 0; mt < 4; ++mt){
    const int k0 = mt*16 + q*4;
    const int off = (((k0 >> 3) ^ rs) << 3) + (k0 & 7);
    v4h w0 = *(const v4h*)(Wl1T + k0);
    v4h w1 = *(const v4h*)(Wl1T + 64 + k0);
    float sA[4], sB[4];
#pragma unroll
    for (int reg = 0; reg < 4; ++reg){
      const float a1A = fmaf(dA0, (float)w0[reg], dA1 * (float)w1[reg]);
      const float a1B = fmaf(dB0, (float)w0[reg], dB1 * (float)w1[reg]);
      sA[reg] = accA[mt][reg] * sreluD(a1A);
      sB[reg] = accB[mt][reg] * sreluD(a1B);
    }
    v4h gA, gB;
    *(v2h*)&gA       = cvt_pk(sA[0], sA[1]);
    *((v2h*)&gA + 1) = cvt_pk(sA[2], sA[3]);
    *(v2h*)&gB       = cvt_pk(sB[0], sB[1]);
    *((v2h*)&gB + 1) = cvt_pk(sB[2], sB[3]);
    *(v4h*)(zioA + lm*64 + off) = gA;
    *(v4h*)(zioB + lm*64 + off) = gB;
  }
}

__device__ __forceinline__ void gacc2(v4f& aGA, v4f& aGB,
    const _Float16* __restrict__ WxTbase,
    const _Float16* ZA, const _Float16* ZB, int lm, int q)
{
  const int rs = lm & 7;
#pragma unroll
  for (int kt = 0; kt < 2; ++kt){
    const int sw = (((kt*4 + q) ^ rs) << 3);
    v8h A  = *(const v8h*)(WxTbase + lm*64 + kt*32 + q*8);
    v8h BA = *(const v8h*)(ZA + lm*64 + sw);
    v8h BB = *(const v8h*)(ZB + lm*64 + sw);
    aGA = __builtin_amdgcn_mfma_f32_16x16x32_f16(A, BA, aGA, 0,0,0);
    aGB = __builtin_amdgcn_mfma_f32_16x16x32_f16(A, BB, aGB, 0,0,0);
  }
}

// ================= merged kernel: fhat -> ff(regs) -> vnet -> combine =================
__global__ __launch_bounds__(512)
__attribute__((amdgpu_waves_per_eu(4, 4)))
void fused_kernel(
  const float* __restrict__ X, const float* __restrict__ Xst,
  const float* __restrict__ Vfx,
  const float* __restrict__ f1b, const float* __restrict__ f2b,
  const float* __restrict__ f3b, const float* __restrict__ f4b,
  const float* __restrict__ f5b, const float* __restrict__ ffb,
  float* __restrict__ out)
{
  __shared__ __align__(16) char smem[65536];   // fhat H 256x128 | vnet 8x8KB/wave
  _Float16* const H = (_Float16*)smem;

  const int b  = blockIdx.x;
  const int t  = threadIdx.x;
  const int w  = t >> 6;     // 0..7
  const int l  = t & 63;
  const int lm = l & 15;
  const int q  = l >> 4;
  const int rs = lm & 7;
  const int row0 = b*256 + w*32;

  const int r0 = row0 + lm;
  const int r1 = row0 + 16 + lm;
  const int rc0 = r0 < NPTS ? r0 : NPTS-1;
  const int rc1 = r1 < NPTS ? r1 : NPTS-1;
  const float2 x0 = *(const float2*)(X + rc0*2);
  const float2 x1 = *(const float2*)(X + rc1*2);

  // ========== fhat phase ==========
  // ---- f1 via MFMA: A = f1w padded to K=32, B = x (q==0 lanes k=0,1) ----
  {
    v8h Bx0 = (v8h){(_Float16)0.f,(_Float16)0.f,(_Float16)0.f,(_Float16)0.f,
                    (_Float16)0.f,(_Float16)0.f,(_Float16)0.f,(_Float16)0.f};
    v8h Bx1 = Bx0;
    if (q == 0){
      Bx0[0] = (_Float16)x0.x; Bx0[1] = (_Float16)x0.y;
      Bx1[0] = (_Float16)x1.x; Bx1[1] = (_Float16)x1.y;
    }
#pragma unroll
    for (int mt = 0; mt < 8; ++mt){
      const int o0 = mt*16 + q*4;
      const v4f bv = *(const v4f*)(f1b + o0);
      v8h A = *(const v8h*)(g_w16 + OFF_F1P + (mt*16 + lm)*32 + q*8);
      v4f a0 = __builtin_amdgcn_mfma_f32_16x16x32_f16(A, Bx0, bv, 0,0,0);
      v4f a1 = __builtin_amdgcn_mfma_f32_16x16x32_f16(A, Bx1, bv, 0,0,0);
      const int coff = (((o0 >> 3) ^ lm) << 3) + (o0 & 7);
      v4h h0, h1;
      *(v2h*)&h0       = lrelu_pk(a0[0], a0[1]);
      *((v2h*)&h0 + 1) = lrelu_pk(a0[2], a0[3]);
      *(v2h*)&h1       = lrelu_pk(a1[0], a1[1]);
      *((v2h*)&h1 + 1) = lrelu_pk(a1[2], a1[3]);
      *(v4h*)(H + (w*32 + lm)*128 + coff)      = h0;
      *(v4h*)(H + (w*32 + 16 + lm)*128 + coff) = h1;
    }
  }
  BAR_LDS();

  fh_layer(H, g_w16 + OFF_FW,         f2b, w, lm, q);
  fh_layer(H, g_w16 + OFF_FW + 16384, f3b, w, lm, q);
  fh_layer(H, g_w16 + OFF_FW + 32768, f4b, w, lm, q);
  fh_layer(H, g_w16 + OFF_FW + 49152, f5b, w, lm, q);

  // ---- ff via MFMA on the wave's OWN rows (w*32..w*32+31) ----
  float fhA0, fhA1, fhB0, fhB1;
  {
    v4f a0 = (v4f){0.f,0.f,0.f,0.f};
    v4f a1 = (v4f){0.f,0.f,0.f,0.f};
#pragma unroll
    for (int kt = 0; kt < 4; ++kt){
      const int sw = ((kt*4 + q) ^ lm) << 3;
      v8h A  = *(const v8h*)(g_w16 + OFF_FFW + lm*128 + kt*32 + q*8);
      v8h B0 = *(const v8h*)(H + (w*32 + lm)*128 + sw);
      v8h B1 = *(const v8h*)(H + (w*32 + 16 + lm)*128 + sw);
      a0 = __builtin_amdgcn_mfma_f32_16x16x32_f16(A, B0, a0, 0,0,0);
      a1 = __builtin_amdgcn_mfma_f32_16x16x32_f16(A, B1, a1, 0,0,0);
    }
    const float fb0 = ffb[0], fb1 = ffb[1];
    fhA0 = a0[0] + fb0; fhA1 = a0[1] + fb1;
    fhB0 = a1[0] + fb0; fhB1 = a1[1] + fb1;
  }

  // ========== vnet phase (wave-local slice) ==========
  _Float16* const ZA2 = (_Float16*)(smem + w*8192);
  _Float16* const ZA3 = ZA2 + 1024;
  _Float16* const ZB2 = ZA2 + 2048;
  _Float16* const ZB3 = ZA2 + 3072;

  const float2 sA = *(const float2*)(Xst + rc0*2);
  const float2 sB = *(const float2*)(Xst + rc1*2);
  const float dA0 = x0.x - sA.x, dA1 = x0.y - sA.y;
  const float dB0 = x1.x - sB.x, dB1 = x1.y - sB.y;
  const float vfx0 = Vfx[0], vfx1 = Vfx[1];

  // d B-fragments for the Wx@d MFMA fold (q==0 lanes carry k=0,1)
  v8h BdA = (v8h){(_Float16)0.f,(_Float16)0.f,(_Float16)0.f,(_Float16)0.f,
                  (_Float16)0.f,(_Float16)0.f,(_Float16)0.f,(_Float16)0.f};
  v8h BdB = BdA;
  if (q == 0){
    BdA[0] = (_Float16)dA0; BdA[1] = (_Float16)dA1;
    BdB[0] = (_Float16)dB0; BdB[1] = (_Float16)dB1;
  }

  // fwd: z2 (z1 in registers, srelu'(a2) carried out), z3
  float sdA2[16], sdB2[16];
  vfwd2_l2(ZA2, ZB2, g_w16 + OFF_V2Z, g_w16 + OFF_V2XP, g_w16 + OFF_VL1T,
           BdA, BdB, dA0, dA1, dB0, dB1, sdA2, sdB2, lm, q);
  vfwd2(ZA2, ZA3, ZB2, ZB3, g_w16 + OFF_V3Z, g_w16 + OFF_V3XP,
        BdA, BdB, lm, q);

  // zf head for both (A row 0 = Vfz)
  float VVrA, sfA, VVrB, sfB;
  {
    v4f aSA = (v4f){0.f,0.f,0.f,0.f};
    v4f aSB = (v4f){0.f,0.f,0.f,0.f};
#pragma unroll
    for (int kt = 0; kt < 2; ++kt){
      const int sw = (((kt*4 + q) ^ rs) << 3);
      v8h A  = *(const v8h*)(g_w16 + OFF_VFZ + lm*64 + kt*32 + q*8);
      v8h BA = *(const v8h*)(ZA3 + lm*64 + sw);
      v8h BB = *(const v8h*)(ZB3 + lm*64 + sw);
      aSA = __builtin_amdgcn_mfma_f32_16x16x32_f16(A, BA, aSA, 0,0,0);
      aSB = __builtin_amdgcn_mfma_f32_16x16x32_f16(A, BB, aSB, 0,0,0);
    }
    const float afA = fmaf(vfx0, dA0, fmaf(vfx1, dA1, aSA[0]));
    const float zfA = srelu(afA);
    VVrA = srelu(zfA) + 0.01f * fmaf(dA0, dA0, dA1*dA1);
    sfA  = sreluD(zfA) * sreluD(afA);
    const float afB = fmaf(vfx0, dB0, fmaf(vfx1, dB1, aSB[0]));
    const float zfB = srelu(afB);
    VVrB = srelu(zfB) + 0.01f * fmaf(dB0, dB0, dB1*dB1);
    sfB  = sreluD(zfB) * sreluD(afB);
  }

  // u3 = Vfz * srelu'(a3) (sf deferred; in place over Z3)
#pragma unroll
  for (int cc = 0; cc < 2; ++cc){
    const int c = q*2 + cc;
    const int sw = ((c ^ rs) << 3);
    v8h vf = *(const v8h*)(g_w16 + OFF_VFZ + c*8);
    _Float16* pA = ZA3 + lm*64 + sw;
    _Float16* pB = ZB3 + lm*64 + sw;
    v8h zA = *(const v8h*)pA;
    v8h zB = *(const v8h*)pB;
    v8h uA, uB;
#pragma unroll
    for (int j2 = 0; j2 < 4; ++j2){
      float a0 = (float)vf[2*j2  ] * sreluD_from_z((float)zA[2*j2  ]);
      float a1 = (float)vf[2*j2+1] * sreluD_from_z((float)zA[2*j2+1]);
      float b0 = (float)vf[2*j2  ] * sreluD_from_z((float)zB[2*j2  ]);
      float b1 = (float)vf[2*j2+1] * sreluD_from_z((float)zB[2*j2+1]);
      ((v2h*)&uA)[j2] = cvt_pk(a0, a1);
      ((v2h*)&uB)[j2] = cvt_pk(b0, b1);
    }
    *(v8h*)pA = uA;
    *(v8h*)pB = uB;
  }

  // incremental gradV, interleaved with backward (arena reuse)
  v4f aGA = (v4f){0.f,0.f,0.f,0.f};
  v4f aGB = (v4f){0.f,0.f,0.f,0.f};

  gacc2(aGA, aGB, g_w16 + OFF_V3XT, ZA3, ZB3, lm, q);             // L3 (ga3=u3)
  vbwd2(ZA3, ZA2, ZB3, ZB2, g_w16 + OFF_V3ZT, sdA2, sdB2, lm, q); // ga2 -> Z2
  gacc2(aGA, aGB, g_w16 + OFF_V2XT, ZA2, ZB2, lm, q);             // L2
  vbwd2_l1(ZA2, ZB2, g_w16 + OFF_V2ZT, g_w16 + OFF_VL1T,
           dA0, dA1, dB0, dB1, lm, q);                            // ga1 -> Z2
  gacc2(aGA, aGB, g_w16 + OFF_VL1T, ZA2, ZB2, lm, q);             // L1

  const float g0A = fmaf(0.02f, dA0, sfA * (vfx0 + aGA[0]));
  const float g1A = fmaf(0.02f, dA1, sfA * (vfx1 + aGA[1]));
  const float g0B = fmaf(0.02f, dB0, sfB * (vfx0 + aGB[0]));
  const float g1B = fmaf(0.02f, dB1, sfB * (vfx1 + aGB[1]));

  // ========== combine in registers, store out ==========
  if (q == 0){
    if (r0 < NPTS){
      const float Vn  = fmaf(g0A, g0A, g1A*g1A);
      const float num = fmaf(0.1f, VVrA, fmaf(fhA0, g0A, fhA1*g1A));
      const float fm  = fmaxf(num, 0.f) / (Vn + 1e-10f);
      *(float2*)(out + r0*2) =
        make_float2(fmaf(-g0A, fm, fhA0), fmaf(-g1A, fm, fhA1));
    }
    if (r1 < NPTS){
      const float Vn  = fmaf(g0B, g0B, g1B*g1B);
      const float num = fmaf(0.1f, VVrB, fmaf(fhB0, g0B, fhB1*g1B));
      const float fm  = fmaxf(num, 0.f) / (Vn + 1e-10f);
      *(float2*)(out + r1*2) =
        make_float2(fmaf(-g0B, fm, fhB0), fmaf(-g1B, fm, fhB1));
    }
  }
}

extern "C" void kernel_launch(void* const* d_in, const int* in_sizes, int n_in,
                              void* d_out, int out_size, void* d_ws, size_t ws_size,
                              hipStream_t stream)
{
  (void)d_ws; (void)ws_size; (void)n_in; (void)in_sizes; (void)out_size;
  const float* X   = (const float*)d_in[0];
  const float* Xst = (const float*)d_in[1];
  const float* Vl1 = (const float*)d_in[2];
  const float* V2x = (const float*)d_in[3];
  const float* V2z = (const float*)d_in[4];
  const float* V3x = (const float*)d_in[5];
  const float* V3z = (const float*)d_in[6];
  const float* Vfx = (const float*)d_in[7];
  const float* Vfz = (const float*)d_in[8];
  const float* f1w = (const float*)d_in[9];
  const float* f1b = (const float*)d_in[10];
  const float* f2w = (const float*)d_in[11];
  const float* f2b = (const float*)d_in[12];
  const float* f3w = (const float*)d_in[13];
  const float* f3b = (const float*)d_in[14];
  const float* f4w = (const float*)d_in[15];
  const float* f4b = (const float*)d_in[16];
  const float* f5w = (const float*)d_in[17];
  const float* f5b = (const float*)d_in[18];
  const float* ffw = (const float*)d_in[19];
  const float* ffb = (const float*)d_in[20];

  prep_kernel<<<(W16_TOTAL + 255)/256, 256, 0, stream>>>(
      f2w, f3w, f4w, f5w, V2z, V3z, Vl1, V2x, V3x, Vfz, ffw, f1w);
  fused_kernel<<<FUSED_GRID, 512, 0, stream>>>(
      X, Xst, Vfx, f1b, f2b, f3b, f4b, f5b, ffb, (float*)d_out);
}

// Round 9
// 253.299 us; speedup vs baseline: 1.1083x; 1.0137x over previous
//
#include <hip/hip_runtime.h>

// ICNN_net_1503238553972 — round 27: register diet + clean allocator pin.
// R26 showed amdgpu_waves_per_eu(4,4) was ignored next to __launch_bounds__
// (VGPR stuck at 64; sd-carry spill traffic FETCH+1MB/WRITE+4MB remains).
// Two-sided fix:
//  (1) sd2 carry packed f16: srelu_pk's internal c=clamp(x,0,1) IS the
//      derivative — capture it (4x v4h per pipeline = 4 regs, was 16 f32).
//      vbwd2 multiplies packed: g = cvt_pk(acc) * sd_h. ~24 fewer live
//      VGPRs in the backward, zero added VALU.
//  (2) attributes only (no __launch_bounds__): flat_work_group_size(512,512)
//      + waves_per_eu(4,4) so the pin is not overridden.
// Everything else identical to R24/R26 (best: 184.5us fused). Grid 1954.

typedef _Float16 v2h __attribute__((ext_vector_type(2)));
typedef __fp16   v2hf __attribute__((ext_vector_type(2)));
typedef _Float16 v4h __attribute__((ext_vector_type(4)));
typedef _Float16 v8h __attribute__((ext_vector_type(8)));
typedef float    v4f __attribute__((ext_vector_type(4)));

__device__ __forceinline__ v2h cvt_pk(float a, float b){
  v2hf r = __builtin_amdgcn_cvt_pkrtz(a, b);
  union { v2hf f; v2h h; } u; u.f = r;
  return u.h;
}

#define NPTS 500000
#define FUSED_GRID ((NPTS + 255) / 256)   // 1954

// LDS-only barrier: LDS ordering without draining vmcnt (weights in flight)
#define BAR_LDS() asm volatile("s_waitcnt lgkmcnt(0)\n\ts_barrier" ::: "memory")

// offsets in halves inside g_w16
#define OFF_FW    0               // f2..f5: L*16384, [o*128+k]
#define OFF_V2Z   65536           // [j*64+k]
#define OFF_V3Z   69632
#define OFF_V2ZT  73728           // [k*64+j]
#define OFF_V3ZT  77824
#define OFF_VL1T  81920           // [c*64+j]
#define OFF_V2XT  82048
#define OFF_V3XT  82176
#define OFF_VFZ   82304           // [64]
#define OFF_FFW   82368           // [c*128+k]
#define OFF_F1W   82624           // [oc*2+c]
#define OFF_F1P   82880           // f1 padded [o*32+k], k<2 valid else 0
#define OFF_V2XP  86976           // V2x padded [o*32+k], k<2 valid else 0
#define OFF_V3XP  89024           // V3x padded [o*32+k], k<2 valid else 0
#define W16_DATA  91072
#define W16_TOTAL (W16_DATA + 2048)   // zero pad: junk A-rows stay in-bounds

__device__ __align__(16) _Float16 g_w16[W16_TOTAL];

__device__ __forceinline__ float srelu(float x){
  float c = fminf(fmaxf(x, 0.f), 1.f);
  return c * fmaf(-0.5f, c, x);
}
__device__ __forceinline__ float sreluD(float x){
  return fminf(fmaxf(x, 0.f), 1.f);
}
__device__ __forceinline__ float sreluD_from_z(float z){
  return fminf(sqrtf(2.f * z), 1.f);
}

// ---- packed f16 activations (2 f32 in -> 2 f16 out) ----
__device__ __forceinline__ v2h lrelu_pk(float a, float b){
  v2h x = cvt_pk(a, b);
  v2h m = x * (v2h){(_Float16)0.01f, (_Float16)0.01f};
  return __builtin_elementwise_max(x, m);
}
__device__ __forceinline__ v2h srelu_pk(float a, float b){
  v2h x = cvt_pk(a, b);
  const v2h z0 = (v2h){(_Float16)0.f, (_Float16)0.f};
  const v2h o1 = (v2h){(_Float16)1.f, (_Float16)1.f};
  const v2h hf = (v2h){(_Float16)0.5f, (_Float16)0.5f};
  v2h c = __builtin_elementwise_min(__builtin_elementwise_max(x, z0), o1);
  v2h t = x - c * hf;
  return c * t;
}
// srelu + expose c = clamp(x,0,1) (== srelu' of the pre-activation, f16)
__device__ __forceinline__ v2h srelu_pk_c(float a, float b, v2h* c_out){
  v2h x = cvt_pk(a, b);
  const v2h z0 = (v2h){(_Float16)0.f, (_Float16)0.f};
  const v2h o1 = (v2h){(_Float16)1.f, (_Float16)1.f};
  const v2h hf = (v2h){(_Float16)0.5f, (_Float16)0.5f};
  v2h c = __builtin_elementwise_min(__builtin_elementwise_max(x, z0), o1);
  *c_out = c;
  v2h t = x - c * hf;
  return c * t;
}

// ---------------- prep: fp32 weights -> f16 layouts (+zero pad) ----------------
__global__ __launch_bounds__(256) void prep_kernel(
  const float* __restrict__ f2w, const float* __restrict__ f3w,
  const float* __restrict__ f4w, const float* __restrict__ f5w,
  const float* __restrict__ V2z, const float* __restrict__ V3z,
  const float* __restrict__ Vl1, const float* __restrict__ V2x,
  const float* __restrict__ V3x, const float* __restrict__ Vfz,
  const float* __restrict__ ffw, const float* __restrict__ f1w)
{
  const int i = blockIdx.x * 256 + threadIdx.x;
  if (i >= W16_TOTAL) return;
  if (i >= W16_DATA){ g_w16[i] = (_Float16)0.f; return; }
  float v;
  if (i < 65536){
    const float* W[4] = {f2w, f3w, f4w, f5w};
    v = W[i >> 14][i & 16383];
  } else if (i < 69632)  v = V2z[i - 65536];
  else if (i < 73728)    v = V3z[i - 69632];
  else if (i < 77824){ int r = i - 73728; v = V2z[(r & 63)*64 + (r >> 6)]; }
  else if (i < 81920){ int r = i - 77824; v = V3z[(r & 63)*64 + (r >> 6)]; }
  else if (i < 82048){ int r = i - 81920; v = Vl1[(r & 63)*2 + (r >> 6)]; }
  else if (i < 82176){ int r = i - 82048; v = V2x[(r & 63)*2 + (r >> 6)]; }
  else if (i < 82304){ int r = i - 82176; v = V3x[(r & 63)*2 + (r >> 6)]; }
  else if (i < 82368)    v = Vfz[i - 82304];
  else if (i < 82624)    v = ffw[i - 82368];
  else if (i < 82880)    v = f1w[i - 82624];
  else if (i < 86976){ int r = i - 82880; int k = r & 31; v = (k < 2) ? f1w[(r >> 5)*2 + k] : 0.f; }
  else if (i < 89024){ int r = i - 86976; int k = r & 31; v = (k < 2) ? V2x[(r >> 5)*2 + k] : 0.f; }
  else               { int r = i - 89024; int k = r & 31; v = (k < 2) ? V3x[(r >> 5)*2 + k] : 0.f; }
  g_w16[i] = (_Float16)v;
}

// ================= fhat layer: 512 thr, 256 rows (R23/R24 form) =================
__device__ __forceinline__ void fh_layer(_Float16* H,
    const _Float16* __restrict__ Wl, const float* __restrict__ Bp,
    int w, int lm, int q)
{
  const v4f bv = *(const v4f*)(Bp + w*16 + q*4);
  v4f acc[16];
#pragma unroll
  for (int nt = 0; nt < 16; ++nt) acc[nt] = bv;

#pragma unroll
  for (int kt = 0; kt < 4; ++kt){
    const int sw = ((kt*4 + q) ^ lm) << 3;
    v8h A = *(const v8h*)(Wl + (w*16 + lm)*128 + kt*32 + q*8);
#pragma unroll
    for (int nt = 0; nt < 16; ++nt){
      v8h B = *(const v8h*)(H + (nt*16 + lm)*128 + sw);
      acc[nt] = __builtin_amdgcn_mfma_f32_16x16x32_f16(A, B, acc[nt], 0,0,0);
    }
  }
  BAR_LDS();
  const int o0 = w*16 + q*4;
  const int coff = (((o0 >> 3) ^ lm) << 3) + (o0 & 7);
#pragma unroll
  for (int nt = 0; nt < 16; ++nt){
    v4h hv;
    *(v2h*)&hv       = lrelu_pk(acc[nt][0], acc[nt][1]);
    *((v2h*)&hv + 1) = lrelu_pk(acc[nt][2], acc[nt][3]);
    *(v4h*)(H + (nt*16 + lm)*128 + coff) = hv;
  }
  BAR_LDS();
}

// ================= vnet pieces (ILP-2; Wx@d folded into MFMA) =================
// layer-2 fwd: z1 B-frags in registers; d-term as extra MFMA K-block;
// srelu'(a2) carried out PACKED f16 (sdA/sdB: 4x v4h each).
__device__ __forceinline__ void vfwd2_l2(_Float16* zoutA, _Float16* zoutB,
    const _Float16* __restrict__ Wz,   // V2Z [o][k]
    const _Float16* __restrict__ WxP,  // V2XP [o][32], k<2 valid
    const _Float16* __restrict__ Wl1T, // VL1T [2][64]
    v8h BdA, v8h BdB,
    float dA0, float dA1, float dB0, float dB1,
    v4h* __restrict__ sdA, v4h* __restrict__ sdB,
    int lm, int q)
{
  v4f accA[4], accB[4];
#pragma unroll
  for (int mt = 0; mt < 4; ++mt){
    accA[mt] = (v4f){0.f,0.f,0.f,0.f};
    accB[mt] = (v4f){0.f,0.f,0.f,0.f};
  }
  const int rs = lm & 7;
  // d-term: acc += WxP @ Bd
#pragma unroll
  for (int mt = 0; mt < 4; ++mt){
    v8h Ax = *(const v8h*)(WxP + (mt*16 + lm)*32 + q*8);
    accA[mt] = __builtin_amdgcn_mfma_f32_16x16x32_f16(Ax, BdA, accA[mt], 0,0,0);
    accB[mt] = __builtin_amdgcn_mfma_f32_16x16x32_f16(Ax, BdB, accB[mt], 0,0,0);
  }
#pragma unroll
  for (int kt = 0; kt < 2; ++kt){
    v8h w0 = *(const v8h*)(Wl1T + kt*32 + q*8);
    v8h w1 = *(const v8h*)(Wl1T + 64 + kt*32 + q*8);
    v8h BA, BB;
#pragma unroll
    for (int j2 = 0; j2 < 4; ++j2){
      const float a0 = (float)w0[2*j2  ], a1 = (float)w0[2*j2+1];
      const float c0 = (float)w1[2*j2  ], c1 = (float)w1[2*j2+1];
      ((v2h*)&BA)[j2] = srelu_pk(fmaf(dA0,a0,dA1*c0), fmaf(dA0,a1,dA1*c1));
      ((v2h*)&BB)[j2] = srelu_pk(fmaf(dB0,a0,dB1*c0), fmaf(dB0,a1,dB1*c1));
    }
#pragma unroll
    for (int mt = 0; mt < 4; ++mt){
      v8h A = *(const v8h*)(Wz + (mt*16 + lm)*64 + kt*32 + q*8);
      accA[mt] = __builtin_amdgcn_mfma_f32_16x16x32_f16(A, BA, accA[mt], 0,0,0);
      accB[mt] = __builtin_amdgcn_mfma_f32_16x16x32_f16(A, BB, accB[mt], 0,0,0);
    }
  }
#pragma unroll
  for (int mt = 0; mt < 4; ++mt){
    const int o0 = mt*16 + q*4;
    const int off = (((o0 >> 3) ^ rs) << 3) + (o0 & 7);
    v4h hA, hB;
    *(v2h*)&hA       = srelu_pk_c(accA[mt][0], accA[mt][1], (v2h*)&sdA[mt]);
    *((v2h*)&hA + 1) = srelu_pk_c(accA[mt][2], accA[mt][3], (v2h*)&sdA[mt] + 1);
    *(v2h*)&hB       = srelu_pk_c(accB[mt][0], accB[mt][1], (v2h*)&sdB[mt]);
    *((v2h*)&hB + 1) = srelu_pk_c(accB[mt][2], accB[mt][3], (v2h*)&sdB[mt] + 1);
    *(v4h*)(zoutA + lm*64 + off) = hA;
    *(v4h*)(zoutB + lm*64 + off) = hB;
  }
}

// layer-3 fwd (B from LDS); d-term as extra MFMA K-block
__device__ __forceinline__ void vfwd2(const _Float16* zinA, _Float16* zoutA,
    const _Float16* zinB, _Float16* zoutB,
    const _Float16* __restrict__ Wz,   // V3Z
    const _Float16* __restrict__ WxP,  // V3XP [o][32]
    v8h BdA, v8h BdB, int lm, int q)
{
  v4f accA[4], accB[4];
#pragma unroll
  for (int mt = 0; mt < 4; ++mt){
    accA[mt] = (v4f){0.f,0.f,0.f,0.f};
    accB[mt] = (v4f){0.f,0.f,0.f,0.f};
  }
  const int rs = lm & 7;
#pragma unroll
  for (int mt = 0; mt < 4; ++mt){
    v8h Ax = *(const v8h*)(WxP + (mt*16 + lm)*32 + q*8);
    accA[mt] = __builtin_amdgcn_mfma_f32_16x16x32_f16(Ax, BdA, accA[mt], 0,0,0);
    accB[mt] = __builtin_amdgcn_mfma_f32_16x16x32_f16(Ax, BdB, accB[mt], 0,0,0);
  }
#pragma unroll
  for (int kt = 0; kt < 2; ++kt){
    const int sw = (((kt*4 + q) ^ rs) << 3);
    v8h BA = *(const v8h*)(zinA + lm*64 + sw);
    v8h BB = *(const v8h*)(zinB + lm*64 + sw);
#pragma unroll
    for (int mt = 0; mt < 4; ++mt){
      v8h A = *(const v8h*)(Wz + (mt*16 + lm)*64 + kt*32 + q*8);
      accA[mt] = __builtin_amdgcn_mfma_f32_16x16x32_f16(A, BA, accA[mt], 0,0,0);
      accB[mt] = __builtin_amdgcn_mfma_f32_16x16x32_f16(A, BB, accB[mt], 0,0,0);
    }
  }
#pragma unroll
  for (int mt = 0; mt < 4; ++mt){
    const int o0 = mt*16 + q*4;
    const int off = (((o0 >> 3) ^ rs) << 3) + (o0 & 7);
    v4h hA, hB;
    *(v2h*)&hA       = srelu_pk(accA[mt][0], accA[mt][1]);
    *((v2h*)&hA + 1) = srelu_pk(accA[mt][2], accA[mt][3]);
    *(v2h*)&hB       = srelu_pk(accB[mt][0], accB[mt][1]);
    *((v2h*)&hB + 1) = srelu_pk(accB[mt][2], accB[mt][3]);
    *(v4h*)(zoutA + lm*64 + off) = hA;
    *(v4h*)(zoutB + lm*64 + off) = hB;
  }
}

// backward layer-3->2: srelu'(a2) from packed f16 registers
__device__ __forceinline__ void vbwd2(const _Float16* ginA, _Float16* zioA,
    const _Float16* ginB, _Float16* zioB,
    const _Float16* __restrict__ WT,
    const v4h* __restrict__ sdA, const v4h* __restrict__ sdB,
    int lm, int q)
{
  v4f accA[4], accB[4];
#pragma unroll
  for (int mt = 0; mt < 4; ++mt){
    accA[mt] = (v4f){0.f,0.f,0.f,0.f};
    accB[mt] = (v4f){0.f,0.f,0.f,0.f};
  }
  const int rs = lm & 7;
#pragma unroll
  for (int kt = 0; kt < 2; ++kt){
    const int sw = (((kt*4 + q) ^ rs) << 3);
    v8h BA = *(const v8h*)(ginA + lm*64 + sw);
    v8h BB = *(const v8h*)(ginB + lm*64 + sw);
#pragma unroll
    for (int mt = 0; mt < 4; ++mt){
      v8h A = *(const v8h*)(WT + (mt*16 + lm)*64 + kt*32 + q*8);
      accA[mt] = __builtin_amdgcn_mfma_f32_16x16x32_f16(A, BA, accA[mt], 0,0,0);
      accB[mt] = __builtin_amdgcn_mfma_f32_16x16x32_f16(A, BB, accB[mt], 0,0,0);
    }
  }
#pragma unroll
  for (int mt = 0; mt < 4; ++mt){
    const int k0 = mt*16 + q*4;
    const int off = (((k0 >> 3) ^ rs) << 3) + (k0 & 7);
    v4h gA, gB;
    ((v2h*)&gA)[0] = cvt_pk(accA[mt][0], accA[mt][1]) * ((const v2h*)&sdA[mt])[0];
    ((v2h*)&gA)[1] = cvt_pk(accA[mt][2], accA[mt][3]) * ((const v2h*)&sdA[mt])[1];
    ((v2h*)&gB)[0] = cvt_pk(accB[mt][0], accB[mt][1]) * ((const v2h*)&sdB[mt])[0];
    ((v2h*)&gB)[1] = cvt_pk(accB[mt][2], accB[mt][3]) * ((const v2h*)&sdB[mt])[1];
    *(v4h*)(zioA + lm*64 + off) = gA;
    *(v4h*)(zioB + lm*64 + off) = gB;
  }
}

__device__ __forceinline__ void vbwd2_l1(_Float16* zioA, _Float16* zioB,
    const _Float16* __restrict__ WT,   // V2ZT
    const _Float16* __restrict__ Wl1T, // VL1T [2][64]
    float dA0, float dA1, float dB0, float dB1, int lm, int q)
{
  v4f accA[4], accB[4];
#pragma unroll
  for (int mt = 0; mt < 4; ++mt){
    accA[mt] = (v4f){0.f,0.f,0.f,0.f};
    accB[mt] = (v4f){0.f,0.f,0.f,0.f};
  }
  const int rs = lm & 7;
#pragma unroll
  for (int kt = 0; kt < 2; ++kt){
    const int sw = (((kt*4 + q) ^ rs) << 3);
    v8h BA = *(const v8h*)(zioA + lm*64 + sw);
    v8h BB = *(const v8h*)(zioB + lm*64 + sw);
#pragma unroll
    for (int mt = 0; mt < 4; ++mt){
      v8h A = *(const v8h*)(WT + (mt*16 + lm)*64 + kt*32 + q*8);
      accA[mt] = __builtin_amdgcn_mfma_f32_16x16x32_f16(A, BA, accA[mt], 0,0,0);
      accB[mt] = __builtin_amdgcn_mfma_f32_16x16x32_f16(A, BB, accB[mt], 0,0,0);
    }
  }
#pragma unroll
  for (int mt = 0; mt < 4; ++mt){
    const int k0 = mt*16 + q*4;
    const int off = (((k0 >> 3) ^ rs) << 3) + (k0 & 7);
    v4h w0 = *(const v4h*)(Wl1T + k0);
    v4h w1 = *(const v4h*)(Wl1T + 64 + k0);
    float sA[4], sB[4];
#pragma unroll
    for (int reg = 0; reg < 4; ++reg){
      const float a1A = fmaf(dA0, (float)w0[reg], dA1 * (float)w1[reg]);
      const float a1B = fmaf(dB0, (float)w0[reg], dB1 * (float)w1[reg]);
      sA[reg] = accA[mt][reg] * sreluD(a1A);
      sB[reg] = accB[mt][reg] * sreluD(a1B);
    }
    v4h gA, gB;
    *(v2h*)&gA       = cvt_pk(sA[0], sA[1]);
    *((v2h*)&gA + 1) = cvt_pk(sA[2], sA[3]);
    *(v2h*)&gB       = cvt_pk(sB[0], sB[1]);
    *((v2h*)&gB + 1) = cvt_pk(sB[2], sB[3]);
    *(v4h*)(zioA + lm*64 + off) = gA;
    *(v4h*)(zioB + lm*64 + off) = gB;
  }
}

__device__ __forceinline__ void gacc2(v4f& aGA, v4f& aGB,
    const _Float16* __restrict__ WxTbase,
    const _Float16* ZA, const _Float16* ZB, int lm, int q)
{
  const int rs = lm & 7;
#pragma unroll
  for (int kt = 0; kt < 2; ++kt){
    const int sw = (((kt*4 + q) ^ rs) << 3);
    v8h A  = *(const v8h*)(WxTbase + lm*64 + kt*32 + q*8);
    v8h BA = *(const v8h*)(ZA + lm*64 + sw);
    v8h BB = *(const v8h*)(ZB + lm*64 + sw);
    aGA = __builtin_amdgcn_mfma_f32_16x16x32_f16(A, BA, aGA, 0,0,0);
    aGB = __builtin_amdgcn_mfma_f32_16x16x32_f16(A, BB, aGB, 0,0,0);
  }
}

// ================= merged kernel: fhat -> ff(regs) -> vnet -> combine =================
__global__
__attribute__((amdgpu_flat_work_group_size(512, 512)))
__attribute__((amdgpu_waves_per_eu(4, 4)))
void fused_kernel(
  const float* __restrict__ X, const float* __restrict__ Xst,
  const float* __restrict__ Vfx,
  const float* __restrict__ f1b, const float* __restrict__ f2b,
  const float* __restrict__ f3b, const float* __restrict__ f4b,
  const float* __restrict__ f5b, const float* __restrict__ ffb,
  float* __restrict__ out)
{
  __shared__ __align__(16) char smem[65536];   // fhat H 256x128 | vnet 8x8KB/wave
  _Float16* const H = (_Float16*)smem;

  const int b  = blockIdx.x;
  const int t  = threadIdx.x;
  const int w  = t >> 6;     // 0..7
  const int l  = t & 63;
  const int lm = l & 15;
  const int q  = l >> 4;
  const int rs = lm & 7;
  const int row0 = b*256 + w*32;

  const int r0 = row0 + lm;
  const int r1 = row0 + 16 + lm;
  const int rc0 = r0 < NPTS ? r0 : NPTS-1;
  const int rc1 = r1 < NPTS ? r1 : NPTS-1;
  const float2 x0 = *(const float2*)(X + rc0*2);
  const float2 x1 = *(const float2*)(X + rc1*2);

  // ========== fhat phase ==========
  // ---- f1 via MFMA: A = f1w padded to K=32, B = x (q==0 lanes k=0,1) ----
  {
    v8h Bx0 = (v8h){(_Float16)0.f,(_Float16)0.f,(_Float16)0.f,(_Float16)0.f,
                    (_Float16)0.f,(_Float16)0.f,(_Float16)0.f,(_Float16)0.f};
    v8h Bx1 = Bx0;
    if (q == 0){
      Bx0[0] = (_Float16)x0.x; Bx0[1] = (_Float16)x0.y;
      Bx1[0] = (_Float16)x1.x; Bx1[1] = (_Float16)x1.y;
    }
#pragma unroll
    for (int mt = 0; mt < 8; ++mt){
      const int o0 = mt*16 + q*4;
      const v4f bv = *(const v4f*)(f1b + o0);
      v8h A = *(const v8h*)(g_w16 + OFF_F1P + (mt*16 + lm)*32 + q*8);
      v4f a0 = __builtin_amdgcn_mfma_f32_16x16x32_f16(A, Bx0, bv, 0,0,0);
      v4f a1 = __builtin_amdgcn_mfma_f32_16x16x32_f16(A, Bx1, bv, 0,0,0);
      const int coff = (((o0 >> 3) ^ lm) << 3) + (o0 & 7);
      v4h h0, h1;
      *(v2h*)&h0       = lrelu_pk(a0[0], a0[1]);
      *((v2h*)&h0 + 1) = lrelu_pk(a0[2], a0[3]);
      *(v2h*)&h1       = lrelu_pk(a1[0], a1[1]);
      *((v2h*)&h1 + 1) = lrelu_pk(a1[2], a1[3]);
      *(v4h*)(H + (w*32 + lm)*128 + coff)      = h0;
      *(v4h*)(H + (w*32 + 16 + lm)*128 + coff) = h1;
    }
  }
  BAR_LDS();

  fh_layer(H, g_w16 + OFF_FW,         f2b, w, lm, q);
  fh_layer(H, g_w16 + OFF_FW + 16384, f3b, w, lm, q);
  fh_layer(H, g_w16 + OFF_FW + 32768, f4b, w, lm, q);
  fh_layer(H, g_w16 + OFF_FW + 49152, f5b, w, lm, q);

  // ---- ff via MFMA on the wave's OWN rows (w*32..w*32+31) ----
  float fhA0, fhA1, fhB0, fhB1;
  {
    v4f a0 = (v4f){0.f,0.f,0.f,0.f};
    v4f a1 = (v4f){0.f,0.f,0.f,0.f};
#pragma unroll
    for (int kt = 0; kt < 4; ++kt){
      const int sw = ((kt*4 + q) ^ lm) << 3;
      v8h A  = *(const v8h*)(g_w16 + OFF_FFW + lm*128 + kt*32 + q*8);
      v8h B0 = *(const v8h*)(H + (w*32 + lm)*128 + sw);
      v8h B1 = *(const v8h*)(H + (w*32 + 16 + lm)*128 + sw);
      a0 = __builtin_amdgcn_mfma_f32_16x16x32_f16(A, B0, a0, 0,0,0);
      a1 = __builtin_amdgcn_mfma_f32_16x16x32_f16(A, B1, a1, 0,0,0);
    }
    const float fb0 = ffb[0], fb1 = ffb[1];
    fhA0 = a0[0] + fb0; fhA1 = a0[1] + fb1;
    fhB0 = a1[0] + fb0; fhB1 = a1[1] + fb1;
  }

  // ========== vnet phase (wave-local slice) ==========
  _Float16* const ZA2 = (_Float16*)(smem + w*8192);
  _Float16* const ZA3 = ZA2 + 1024;
  _Float16* const ZB2 = ZA2 + 2048;
  _Float16* const ZB3 = ZA2 + 3072;

  const float2 sA = *(const float2*)(Xst + rc0*2);
  const float2 sB = *(const float2*)(Xst + rc1*2);
  const float dA0 = x0.x - sA.x, dA1 = x0.y - sA.y;
  const float dB0 = x1.x - sB.x, dB1 = x1.y - sB.y;
  const float vfx0 = Vfx[0], vfx1 = Vfx[1];

  // d B-fragments for the Wx@d MFMA fold (q==0 lanes carry k=0,1)
  v8h BdA = (v8h){(_Float16)0.f,(_Float16)0.f,(_Float16)0.f,(_Float16)0.f,
                  (_Float16)0.f,(_Float16)0.f,(_Float16)0.f,(_Float16)0.f};
  v8h BdB = BdA;
  if (q == 0){
    BdA[0] = (_Float16)dA0; BdA[1] = (_Float16)dA1;
    BdB[0] = (_Float16)dB0; BdB[1] = (_Float16)dB1;
  }

  // fwd: z2 (z1 in registers, srelu'(a2) carried packed f16), z3
  v4h sdA2[4], sdB2[4];
  vfwd2_l2(ZA2, ZB2, g_w16 + OFF_V2Z, g_w16 + OFF_V2XP, g_w16 + OFF_VL1T,
           BdA, BdB, dA0, dA1, dB0, dB1, sdA2, sdB2, lm, q);
  vfwd2(ZA2, ZA3, ZB2, ZB3, g_w16 + OFF_V3Z, g_w16 + OFF_V3XP,
        BdA, BdB, lm, q);

  // zf head for both (A row 0 = Vfz)
  float VVrA, sfA, VVrB, sfB;
  {
    v4f aSA = (v4f){0.f,0.f,0.f,0.f};
    v4f aSB = (v4f){0.f,0.f,0.f,0.f};
#pragma unroll
    for (int kt = 0; kt < 2; ++kt){
      const int sw = (((kt*4 + q) ^ rs) << 3);
      v8h A  = *(const v8h*)(g_w16 + OFF_VFZ + lm*64 + kt*32 + q*8);
      v8h BA = *(const v8h*)(ZA3 + lm*64 + sw);
      v8h BB = *(const v8h*)(ZB3 + lm*64 + sw);
      aSA = __builtin_amdgcn_mfma_f32_16x16x32_f16(A, BA, aSA, 0,0,0);
      aSB = __builtin_amdgcn_mfma_f32_16x16x32_f16(A, BB, aSB, 0,0,0);
    }
    const float afA = fmaf(vfx0, dA0, fmaf(vfx1, dA1, aSA[0]));
    const float zfA = srelu(afA);
    VVrA = srelu(zfA) + 0.01f * fmaf(dA0, dA0, dA1*dA1);
    sfA  = sreluD(zfA) * sreluD(afA);
    const float afB = fmaf(vfx0, dB0, fmaf(vfx1, dB1, aSB[0]));
    const float zfB = srelu(afB);
    VVrB = srelu(zfB) + 0.01f * fmaf(dB0, dB0, dB1*dB1);
    sfB  = sreluD(zfB) * sreluD(afB);
  }

  // u3 = Vfz * srelu'(a3) (sf deferred; in place over Z3)
#pragma unroll
  for (int cc = 0; cc < 2; ++cc){
    const int c = q*2 + cc;
    const int sw = ((c ^ rs) << 3);
    v8h vf = *(const v8h*)(g_w16 + OFF_VFZ + c*8);
    _Float16* pA = ZA3 + lm*64 + sw;
    _Float16* pB = ZB3 + lm*64 + sw;
    v8h zA = *(const v8h*)pA;
    v8h zB = *(const v8h*)pB;
    v8h uA, uB;
#pragma unroll
    for (int j2 = 0; j2 < 4; ++j2){
      float a0 = (float)vf[2*j2  ] * sreluD_from_z((float)zA[2*j2  ]);
      float a1 = (float)vf[2*j2+1] * sreluD_from_z((float)zA[2*j2+1]);
      float b0 = (float)vf[2*j2  ] * sreluD_from_z((float)zB[2*j2  ]);
      float b1 = (float)vf[2*j2+1] * sreluD_from_z((float)zB[2*j2+1]);
      ((v2h*)&uA)[j2] = cvt_pk(a0, a1);
      ((v2h*)&uB)[j2] = cvt_pk(b0, b1);
    }
    *(v8h*)pA = uA;
    *(v8h*)pB = uB;
  }

  // incremental gradV, interleaved with backward (arena reuse)
  v4f aGA = (v4f){0.f,0.f,0.f,0.f};
  v4f aGB = (v4f){0.f,0.f,0.f,0.f};

  gacc2(aGA, aGB, g_w16 + OFF_V3XT, ZA3, ZB3, lm, q);             // L3 (ga3=u3)
  vbwd2(ZA3, ZA2, ZB3, ZB2, g_w16 + OFF_V3ZT, sdA2, sdB2, lm, q); // ga2 -> Z2
  gacc2(aGA, aGB, g_w16 + OFF_V2XT, ZA2, ZB2, lm, q);             // L2
  vbwd2_l1(ZA2, ZB2, g_w16 + OFF_V2ZT, g_w16 + OFF_VL1T,
           dA0, dA1, dB0, dB1, lm, q);                            // ga1 -> Z2
  gacc2(aGA, aGB, g_w16 + OFF_VL1T, ZA2, ZB2, lm, q);             // L1

  const float g0A = fmaf(0.02f, dA0, sfA * (vfx0 + aGA[0]));
  const float g1A = fmaf(0.02f, dA1, sfA * (vfx1 + aGA[1]));
  const float g0B = fmaf(0.02f, dB0, sfB * (vfx0 + aGB[0]));
  const float g1B = fmaf(0.02f, dB1, sfB * (vfx1 + aGB[1]));

  // ========== combine in registers, store out ==========
  if (q == 0){
    if (r0 < NPTS){
      const float Vn  = fmaf(g0A, g0A, g1A*g1A);
      const float num = fmaf(0.1f, VVrA, fmaf(fhA0, g0A, fhA1*g1A));
      const float fm  = fmaxf(num, 0.f) / (Vn + 1e-10f);
      *(float2*)(out + r0*2) =
        make_float2(fmaf(-g0A, fm, fhA0), fmaf(-g1A, fm, fhA1));
    }
    if (r1 < NPTS){
      const float Vn  = fmaf(g0B, g0B, g1B*g1B);
      const float num = fmaf(0.1f, VVrB, fmaf(fhB0, g0B, fhB1*g1B));
      const float fm  = fmaxf(num, 0.f) / (Vn + 1e-10f);
      *(float2*)(out + r1*2) =
        make_float2(fmaf(-g0B, fm, fhB0), fmaf(-g1B, fm, fhB1));
    }
  }
}

extern "C" void kernel_launch(void* const* d_in, const int* in_sizes, int n_in,
                              void* d_out, int out_size, void* d_ws, size_t ws_size,
                              hipStream_t stream)
{
  (void)d_ws; (void)ws_size; (void)n_in; (void)in_sizes; (void)out_size;
  const float* X   = (const float*)d_in[0];
  const float* Xst = (const float*)d_in[1];
  const float* Vl1 = (const float*)d_in[2];
  const float* V2x = (const float*)d_in[3];
  const float* V2z = (const float*)d_in[4];
  const float* V3x = (const float*)d_in[5];
  const float* V3z = (const float*)d_in[6];
  const float* Vfx = (const float*)d_in[7];
  const float* Vfz = (const float*)d_in[8];
  const float* f1w = (const float*)d_in[9];
  const float* f1b = (const float*)d_in[10];
  const float* f2w = (const float*)d_in[11];
  const float* f2b = (const float*)d_in[12];
  const float* f3w = (const float*)d_in[13];
  const float* f3b = (const float*)d_in[14];
  const float* f4w = (const float*)d_in[15];
  const float* f4b = (const float*)d_in[16];
  const float* f5w = (const float*)d_in[17];
  const float* f5b = (const float*)d_in[18];
  const float* ffw = (const float*)d_in[19];
  const float* ffb = (const float*)d_in[20];

  prep_kernel<<<(W16_TOTAL + 255)/256, 256, 0, stream>>>(
      f2w, f3w, f4w, f5w, V2z, V3z, Vl1, V2x, V3x, Vfz, ffw, f1w);
  fused_kernel<<<FUSED_GRID, 512, 0, stream>>>(
      X, Xst, Vfx, f1b, f2b, f3b, f4b, f5b, ffb, (float*)d_out);
}